// Round 13
// baseline (258.811 us; speedup 1.0000x reference)
//
#include <hip/hip_runtime.h>

#define IN_C 256
#define HIDC 32
#define OUTC 16
#define NPB  128          // nodes per bucket (d_local = 7 bits)
#define MAXBKT 800        // >= ceil(100000/128) = 782

// ---------------- bf16 helpers ---------------------------------------------
__device__ __forceinline__ unsigned bf16pair(float a, float b) {   // RNE pack
    unsigned ua = __float_as_uint(a); ua += 0x7FFF + ((ua >> 16) & 1);
    unsigned ub = __float_as_uint(b); ub += 0x7FFF + ((ub >> 16) & 1);
    return (ua >> 16) | (ub & 0xFFFF0000u);
}
__device__ __forceinline__ float bf16lo(unsigned u) { return __uint_as_float(u << 16); }
__device__ __forceinline__ float bf16hi(unsigned u) { return __uint_as_float(u & 0xFFFF0000u); }

// ---------------- edge index loader (handles int32 or int64 storage) -------
__device__ __forceinline__ int edge_at(const int* __restrict__ ei, long long idx, int is64) {
    return is64 ? ei[idx << 1] : ei[idx];
}

__global__ void k_detect(const int* __restrict__ ei, int* __restrict__ flag) {
    __shared__ int nz;
    if (threadIdx.x == 0) nz = 0;
    __syncthreads();
    if (ei[2 * threadIdx.x + 1] != 0) atomicOr(&nz, 1);
    __syncthreads();
    if (threadIdx.x == 0) *flag = (nz == 0) ? 1 : 0;
}

// ---------------- bucket binning (256 blocks x 1024 thr — round-10/11) -----
__global__ __launch_bounds__(1024) void k_bin_count(const int* __restrict__ ei, long long E,
                                                    const int* __restrict__ flag,
                                                    int* __restrict__ bkt_cnt, int nbkt) {
    __shared__ int hist[MAXBKT];
    int is64 = *flag;
    for (int i = threadIdx.x; i < nbkt; i += 1024) hist[i] = 0;
    __syncthreads();
    long long chunk = (E + gridDim.x - 1) / gridDim.x;
    long long lo = (long long)blockIdx.x * chunk;
    long long hi = lo + chunk; if (hi > E) hi = E;
    for (long long i = lo + threadIdx.x; i < hi; i += 1024)
        atomicAdd(&hist[edge_at(ei, E + i, is64) >> 7], 1);
    __syncthreads();
    for (int b = threadIdx.x; b < nbkt; b += 1024)
        if (hist[b]) atomicAdd(&bkt_cnt[b], hist[b]);
}

__global__ __launch_bounds__(512) void k_bscan(const int* __restrict__ bkt_cnt,
                                               int* __restrict__ bkt_base,
                                               int* __restrict__ bkt_cur, int nbkt) {
    __shared__ int sm[512];
    int t = threadIdx.x;
    int e0 = (2 * t < nbkt) ? bkt_cnt[2 * t] : 0;
    int e1 = (2 * t + 1 < nbkt) ? bkt_cnt[2 * t + 1] : 0;
    int pv = e0 + e1;
    sm[t] = pv;
    __syncthreads();
    for (int o = 1; o < 512; o <<= 1) {
        int x = (t >= o) ? sm[t - o] : 0;
        __syncthreads();
        sm[t] += x;
        __syncthreads();
    }
    int base = sm[t] - pv;
    if (2 * t < nbkt)     { bkt_base[2 * t] = base;          bkt_cur[2 * t] = base; }
    if (2 * t + 1 < nbkt) { bkt_base[2 * t + 1] = base + e0; bkt_cur[2 * t + 1] = base + e0; }
}

__global__ __launch_bounds__(1024) void k_bin_scatter(const int* __restrict__ ei, long long E,
                                                      const int* __restrict__ flag,
                                                      int* __restrict__ bkt_cur,
                                                      unsigned* __restrict__ packed, int nbkt) {
    __shared__ int hist[MAXBKT];
    int is64 = *flag;
    for (int i = threadIdx.x; i < nbkt; i += 1024) hist[i] = 0;
    __syncthreads();
    long long chunk = (E + gridDim.x - 1) / gridDim.x;
    long long lo = (long long)blockIdx.x * chunk;
    long long hi = lo + chunk; if (hi > E) hi = E;
    for (long long i = lo + threadIdx.x; i < hi; i += 1024)
        atomicAdd(&hist[edge_at(ei, E + i, is64) >> 7], 1);
    __syncthreads();
    for (int b = threadIdx.x; b < nbkt; b += 1024) {
        int c = hist[b];
        hist[b] = c ? atomicAdd(&bkt_cur[b], c) : 0;
    }
    __syncthreads();
    for (long long i = lo + threadIdx.x; i < hi; i += 1024) {
        int s = edge_at(ei, i, is64);
        int d = edge_at(ei, E + i, is64);
        int slot = atomicAdd(&hist[d >> 7], 1);
        packed[slot] = (unsigned)s | ((unsigned)(d & (NPB - 1)) << 20);
    }
}

// ---------------- per-bucket counting sort -> node-level CSR ---------------
__global__ __launch_bounds__(256) void k_bucket_csr(const unsigned* __restrict__ packed,
                                                    const int* __restrict__ bkt_base,
                                                    const int* __restrict__ bkt_cnt,
                                                    int* __restrict__ csr_src,
                                                    int* __restrict__ ptr,
                                                    int* __restrict__ cnt,
                                                    float* __restrict__ dinv, int n) {
    __shared__ int hist[NPB];
    __shared__ int off[NPB];
    if (threadIdx.x < NPB) hist[threadIdx.x] = 0;
    __syncthreads();
    int base = bkt_base[blockIdx.x], m = bkt_cnt[blockIdx.x];
    for (int i = threadIdx.x; i < m; i += 256)
        atomicAdd(&hist[packed[base + i] >> 20], 1);
    __syncthreads();
    if (threadIdx.x < NPB) off[threadIdx.x] = hist[threadIdx.x];
    __syncthreads();
    for (int o = 1; o < NPB; o <<= 1) {
        int v = 0;
        if (threadIdx.x < NPB && threadIdx.x >= o) v = off[threadIdx.x - o];
        __syncthreads();
        if (threadIdx.x < NPB) off[threadIdx.x] += v;
        __syncthreads();
    }
    int node = blockIdx.x * NPB + threadIdx.x;
    if (threadIdx.x < NPB) {
        int exc = off[threadIdx.x] - hist[threadIdx.x];
        if (node < n) {
            ptr[node]  = base + exc;
            cnt[node]  = hist[threadIdx.x];
            dinv[node] = rsqrtf((float)hist[threadIdx.x] + 1.0f);
        }
        hist[threadIdx.x] = exc;
    }
    __syncthreads();
    for (int i = threadIdx.x; i < m; i += 256) {
        unsigned w = packed[base + i];
        int r = atomicAdd(&hist[w >> 20], 1);
        csr_src[base + r] = (int)(w & 0xFFFFF);
    }
}

// ---------------- gemm1: h1b = bf16((x @ W1) * dinv)  [n,256]x[256,32] -----
// lane = node; wave q owns o-octet via readfirstlane -> W read on the SCALAR
// path (s_load + v_fmac SGPR operand; round-12 lesson: W-via-LDS-broadcast
// made the kernel LDS-issue-bound, 954 vs 512 cyc/chunk). x double-buffered
// in LDS ([64][36] rows, ds_read_b128), loads issued before compute,
// ONE barrier per chunk.
#define G1_NODES 64
#define FMA8(xv, base) \
    a0 = fmaf(xv, wk[(base) + 0], a0); a1 = fmaf(xv, wk[(base) + 1], a1); \
    a2 = fmaf(xv, wk[(base) + 2], a2); a3 = fmaf(xv, wk[(base) + 3], a3); \
    a4 = fmaf(xv, wk[(base) + 4], a4); a5 = fmaf(xv, wk[(base) + 5], a5); \
    a6 = fmaf(xv, wk[(base) + 6], a6); a7 = fmaf(xv, wk[(base) + 7], a7);

__global__ __launch_bounds__(256) void k_gemm1(const float* __restrict__ x,
                                               const float* __restrict__ W1,
                                               const float* __restrict__ dinv,
                                               unsigned* __restrict__ h1b, int n) {
    __shared__ float xs[2][G1_NODES][36];   // 18.4 KB double buffer
    const int t = threadIdx.x;
    const int lane = t & 63;
    const int oq0 = __builtin_amdgcn_readfirstlane((t >> 6) * 8);  // SGPR
    const long long nb0 = (long long)blockIdx.x * G1_NODES;
    const long long node = nb0 + lane;
    const float* __restrict__ wq = W1 + oq0;       // uniform base -> s_load

    float a0 = 0.f, a1 = 0.f, a2 = 0.f, a3 = 0.f;
    float a4 = 0.f, a5 = 0.f, a6 = 0.f, a7 = 0.f;

    // stage-load/write helpers: 512 float4 per chunk, 2 per thread
    const int srow0 = t >> 3, sc40 = t & 7;          // f = t
    const int srow1 = (256 + t) >> 3, sc41 = t & 7;  // f = 256 + t  (same c4)
    const long long gn0 = nb0 + srow0, gn1 = nb0 + srow1;
    float4 p0, p1;
    auto stage_load = [&](int c) {
        const int k0 = c * 32;
        p0 = make_float4(0.f, 0.f, 0.f, 0.f);
        p1 = make_float4(0.f, 0.f, 0.f, 0.f);
        if (gn0 < n) p0 = *(const float4*)(x + gn0 * IN_C + k0 + sc40 * 4);
        if (gn1 < n) p1 = *(const float4*)(x + gn1 * IN_C + k0 + sc41 * 4);
    };
    auto stage_write = [&](int b) {
        *(float4*)&xs[b][srow0][sc40 * 4] = p0;
        *(float4*)&xs[b][srow1][sc41 * 4] = p1;
    };

    stage_load(0);
    stage_write(0);
    __syncthreads();

#pragma unroll 1
    for (int c = 0; c < IN_C / 32; ++c) {
        if (c < 7) stage_load(c + 1);                // issue early, hide under FMA
        const float* __restrict__ xrow = &xs[c & 1][lane][0];
#pragma unroll
        for (int g = 0; g < 4; ++g) {                // 8 k per group
            float4 xa = *(const float4*)(xrow + g * 8);
            float4 xb = *(const float4*)(xrow + g * 8 + 4);
            const float* __restrict__ wk = wq + (c * 32 + g * 8) * HIDC;
            FMA8(xa.x, 0)   FMA8(xa.y, 32)  FMA8(xa.z, 64)  FMA8(xa.w, 96)
            FMA8(xb.x, 128) FMA8(xb.y, 160) FMA8(xb.z, 192) FMA8(xb.w, 224)
        }
        if (c < 7) {
            stage_write((c + 1) & 1);                // other buffer: no race
            __syncthreads();
        }
    }
    if (node < n) {
        float di = dinv[node];
        uint4 p;
        p.x = bf16pair(a0 * di, a1 * di);
        p.y = bf16pair(a2 * di, a3 * di);
        p.z = bf16pair(a4 * di, a5 * di);
        p.w = bf16pair(a6 * di, a7 * di);
        *(uint4*)(h1b + node * (HIDC / 2) + oq0 / 2) = p;
    }
}

// ---------------- layer-1 pull aggregation (bf16 gathers) ------------------
__global__ __launch_bounds__(256) void k_agg1csr(const int* __restrict__ ptr,
                                                 const int* __restrict__ cnt,
                                                 const int* __restrict__ csr_src,
                                                 const float* __restrict__ dinv,
                                                 const unsigned* __restrict__ h1b,
                                                 const float* __restrict__ b1,
                                                 float* __restrict__ h1r, int n) {
    long long g = (long long)blockIdx.x * blockDim.x + threadIdx.x;
    int node = (int)(g >> 4);
    int cp = (int)(g & 15);              // channel pair
    if (node >= n) return;
    unsigned us = h1b[(long long)node * 16 + cp];
    float accL = bf16lo(us), accH = bf16hi(us);   // self term (pre-scaled)
    int st = ptr[node], deg = cnt[node];
    int j = 0;
    for (; j + 3 < deg; j += 4) {
        int s0 = csr_src[st + j], s1 = csr_src[st + j + 1];
        int s2 = csr_src[st + j + 2], s3 = csr_src[st + j + 3];
        unsigned u0 = h1b[(long long)s0 * 16 + cp];
        unsigned u1 = h1b[(long long)s1 * 16 + cp];
        unsigned u2 = h1b[(long long)s2 * 16 + cp];
        unsigned u3 = h1b[(long long)s3 * 16 + cp];
        accL += (bf16lo(u0) + bf16lo(u1)) + (bf16lo(u2) + bf16lo(u3));
        accH += (bf16hi(u0) + bf16hi(u1)) + (bf16hi(u2) + bf16hi(u3));
    }
    for (; j < deg; ++j) {
        unsigned u = h1b[(long long)csr_src[st + j] * 16 + cp];
        accL += bf16lo(u); accH += bf16hi(u);
    }
    float di = dinv[node];
    float vL = accL * di + b1[2 * cp];
    float vH = accH * di + b1[2 * cp + 1];
    *(float2*)(h1r + (long long)node * HIDC + 2 * cp) =
        make_float2(vL > 0.f ? vL : 0.f, vH > 0.f ? vH : 0.f);
}

// ---------------- gemm2: h2b = bf16((h1r @ W2) * dinv) ---------------------
__global__ __launch_bounds__(256) void k_gemm2(const float* __restrict__ h1,
                                               const float* __restrict__ W2,
                                               const float* __restrict__ dinv,
                                               unsigned* __restrict__ h2b, int n) {
    const int t = threadIdx.x;
    const int oq = (t & 3) * 4;
    const long long node = (long long)blockIdx.x * 64 + (t >> 2);
    if (node >= n) return;
    const float* __restrict__ xp = h1 + node * HIDC;
    float a0 = 0.f, a1 = 0.f, a2 = 0.f, a3 = 0.f;
#pragma unroll
    for (int k0 = 0; k0 < HIDC; k0 += 8) {
        float4 xv0 = *(const float4*)(xp + k0);
        float4 xv1 = *(const float4*)(xp + k0 + 4);
        const float* __restrict__ wp = W2 + (long long)k0 * OUTC + oq;
        float4 w0 = *(const float4*)(wp + 0 * OUTC);
        float4 w1 = *(const float4*)(wp + 1 * OUTC);
        float4 w2 = *(const float4*)(wp + 2 * OUTC);
        float4 w3 = *(const float4*)(wp + 3 * OUTC);
        float4 w4 = *(const float4*)(wp + 4 * OUTC);
        float4 w5 = *(const float4*)(wp + 5 * OUTC);
        float4 w6 = *(const float4*)(wp + 6 * OUTC);
        float4 w7 = *(const float4*)(wp + 7 * OUTC);
        a0 = fmaf(xv0.x, w0.x, a0); a1 = fmaf(xv0.x, w0.y, a1);
        a2 = fmaf(xv0.x, w0.z, a2); a3 = fmaf(xv0.x, w0.w, a3);
        a0 = fmaf(xv0.y, w1.x, a0); a1 = fmaf(xv0.y, w1.y, a1);
        a2 = fmaf(xv0.y, w1.z, a2); a3 = fmaf(xv0.y, w1.w, a3);
        a0 = fmaf(xv0.z, w2.x, a0); a1 = fmaf(xv0.z, w2.y, a1);
        a2 = fmaf(xv0.z, w2.z, a2); a3 = fmaf(xv0.z, w2.w, a3);
        a0 = fmaf(xv0.w, w3.x, a0); a1 = fmaf(xv0.w, w3.y, a1);
        a2 = fmaf(xv0.w, w3.z, a2); a3 = fmaf(xv0.w, w3.w, a3);
        a0 = fmaf(xv1.x, w4.x, a0); a1 = fmaf(xv1.x, w4.y, a1);
        a2 = fmaf(xv1.x, w4.z, a2); a3 = fmaf(xv1.x, w4.w, a3);
        a0 = fmaf(xv1.y, w5.x, a0); a1 = fmaf(xv1.y, w5.y, a1);
        a2 = fmaf(xv1.y, w5.z, a2); a3 = fmaf(xv1.y, w5.w, a3);
        a0 = fmaf(xv1.z, w6.x, a0); a1 = fmaf(xv1.z, w6.y, a1);
        a2 = fmaf(xv1.z, w6.z, a2); a3 = fmaf(xv1.z, w6.w, a3);
        a0 = fmaf(xv1.w, w7.x, a0); a1 = fmaf(xv1.w, w7.y, a1);
        a2 = fmaf(xv1.w, w7.z, a2); a3 = fmaf(xv1.w, w7.w, a3);
    }
    float di = dinv[node];
    uint2 p;
    p.x = bf16pair(a0 * di, a1 * di);
    p.y = bf16pair(a2 * di, a3 * di);
    *(uint2*)(h2b + node * (OUTC / 2) + oq / 2) = p;
}

// ---------------- layer-2 pull aggregation (bf16 gathers) -> d_out ---------
__global__ __launch_bounds__(256) void k_agg2csr(const int* __restrict__ ptr,
                                                 const int* __restrict__ cnt,
                                                 const int* __restrict__ csr_src,
                                                 const float* __restrict__ dinv,
                                                 const unsigned* __restrict__ h2b,
                                                 const float* __restrict__ b2,
                                                 float* __restrict__ out, int n) {
    long long g = (long long)blockIdx.x * blockDim.x + threadIdx.x;
    int node = (int)(g >> 3);
    int cp = (int)(g & 7);
    if (node >= n) return;
    unsigned us = h2b[(long long)node * 8 + cp];
    float accL = bf16lo(us), accH = bf16hi(us);
    int st = ptr[node], deg = cnt[node];
    int j = 0;
    for (; j + 3 < deg; j += 4) {
        int s0 = csr_src[st + j], s1 = csr_src[st + j + 1];
        int s2 = csr_src[st + j + 2], s3 = csr_src[st + j + 3];
        unsigned u0 = h2b[(long long)s0 * 8 + cp];
        unsigned u1 = h2b[(long long)s1 * 8 + cp];
        unsigned u2 = h2b[(long long)s2 * 8 + cp];
        unsigned u3 = h2b[(long long)s3 * 8 + cp];
        accL += (bf16lo(u0) + bf16lo(u1)) + (bf16lo(u2) + bf16lo(u3));
        accH += (bf16hi(u0) + bf16hi(u1)) + (bf16hi(u2) + bf16hi(u3));
    }
    for (; j < deg; ++j) {
        unsigned u = h2b[(long long)csr_src[st + j] * 8 + cp];
        accL += bf16lo(u); accH += bf16hi(u);
    }
    float di = dinv[node];
    *(float2*)(out + (long long)node * OUTC + 2 * cp) =
        make_float2(accL * di + b2[2 * cp], accH * di + b2[2 * cp + 1]);
}

extern "C" void kernel_launch(void* const* d_in, const int* in_sizes, int n_in,
                              void* d_out, int out_size, void* d_ws, size_t ws_size,
                              hipStream_t stream) {
    const float* x  = (const float*)d_in[0];
    const int*   ei = (const int*)d_in[1];
    const float* W1 = (const float*)d_in[2];
    const float* b1 = (const float*)d_in[3];
    const float* W2 = (const float*)d_in[4];
    const float* b2 = (const float*)d_in[5];
    const int n = in_sizes[0] / IN_C;            // 100000
    const long long E = in_sizes[1] / 2;         // 3200000
    float* out = (float*)d_out;

    const int nbkt = (n + NPB - 1) / NPB;        // 782

    char* ws = (char*)d_ws;
    size_t off = 0;
    auto alloc = [&](size_t bytes) { void* p = ws + off; off += (bytes + 255) & ~(size_t)255; return p; };
    int*      flag     = (int*)alloc(256);
    int*      bkt_cnt  = (int*)alloc((size_t)MAXBKT * 4);
    int*      bkt_base = (int*)alloc((size_t)MAXBKT * 4);
    int*      bkt_cur  = (int*)alloc((size_t)MAXBKT * 4);
    float*    dinv     = (float*)alloc((size_t)n * 4);
    int*      cnt      = (int*)alloc((size_t)n * 4);
    int*      ptr      = (int*)alloc((size_t)n * 4);
    unsigned* packed   = (unsigned*)alloc((size_t)E * 4);
    int*      csr_src  = (int*)alloc((size_t)E * 4);
    unsigned* h1b      = (unsigned*)alloc((size_t)n * (HIDC / 2) * 4);  // bf16 [n][32]
    float*    h1r      = (float*)alloc((size_t)n * HIDC * 4);
    unsigned* h2b      = (unsigned*)alloc((size_t)n * (OUTC / 2) * 4);  // bf16 [n][16]

    hipMemsetAsync(bkt_cnt, 0, (size_t)nbkt * 4, stream);

    k_detect<<<1, 256, 0, stream>>>(ei, flag);
    k_bin_count<<<256, 1024, 0, stream>>>(ei, E, flag, bkt_cnt, nbkt);
    k_bscan<<<1, 512, 0, stream>>>(bkt_cnt, bkt_base, bkt_cur, nbkt);
    k_bin_scatter<<<256, 1024, 0, stream>>>(ei, E, flag, bkt_cur, packed, nbkt);
    k_bucket_csr<<<nbkt, 256, 0, stream>>>(packed, bkt_base, bkt_cnt, csr_src, ptr, cnt, dinv, n);

    k_gemm1<<<(n + G1_NODES - 1) / G1_NODES, 256, 0, stream>>>(x, W1, dinv, h1b, n);
    k_agg1csr<<<(int)(((long long)n * 16 + 255) / 256), 256, 0, stream>>>(
        ptr, cnt, csr_src, dinv, h1b, b1, h1r, n);
    k_gemm2<<<(n + 63) / 64, 256, 0, stream>>>(h1r, W2, dinv, h2b, n);
    k_agg2csr<<<(int)(((long long)n * 8 + 255) / 256), 256, 0, stream>>>(
        ptr, cnt, csr_src, dinv, h2b, b2, out, n);
}

// Round 14
// 201.721 us; speedup vs baseline: 1.2830x; 1.2830x over previous
//
#include <hip/hip_runtime.h>

#define IN_C 256
#define HIDC 32
#define OUTC 16
#define NPB  128          // nodes per bucket (d_local = 7 bits)
#define MAXBKT 800        // >= ceil(100000/128) = 782

// ---------------- bf16 helpers ---------------------------------------------
__device__ __forceinline__ unsigned bf16pair(float a, float b) {   // RNE pack
    unsigned ua = __float_as_uint(a); ua += 0x7FFF + ((ua >> 16) & 1);
    unsigned ub = __float_as_uint(b); ub += 0x7FFF + ((ub >> 16) & 1);
    return (ua >> 16) | (ub & 0xFFFF0000u);
}
__device__ __forceinline__ float bf16lo(unsigned u) { return __uint_as_float(u << 16); }
__device__ __forceinline__ float bf16hi(unsigned u) { return __uint_as_float(u & 0xFFFF0000u); }

// ---------------- edge index loader (handles int32 or int64 storage) -------
__device__ __forceinline__ int edge_at(const int* __restrict__ ei, long long idx, int is64) {
    return is64 ? ei[idx << 1] : ei[idx];
}

__global__ void k_detect(const int* __restrict__ ei, int* __restrict__ flag) {
    __shared__ int nz;
    if (threadIdx.x == 0) nz = 0;
    __syncthreads();
    if (ei[2 * threadIdx.x + 1] != 0) atomicOr(&nz, 1);
    __syncthreads();
    if (threadIdx.x == 0) *flag = (nz == 0) ? 1 : 0;
}

// ---------------- bucket binning (256 blocks x 1024 thr — round-10/11) -----
__global__ __launch_bounds__(1024) void k_bin_count(const int* __restrict__ ei, long long E,
                                                    const int* __restrict__ flag,
                                                    int* __restrict__ bkt_cnt, int nbkt) {
    __shared__ int hist[MAXBKT];
    int is64 = *flag;
    for (int i = threadIdx.x; i < nbkt; i += 1024) hist[i] = 0;
    __syncthreads();
    long long chunk = (E + gridDim.x - 1) / gridDim.x;
    long long lo = (long long)blockIdx.x * chunk;
    long long hi = lo + chunk; if (hi > E) hi = E;
    for (long long i = lo + threadIdx.x; i < hi; i += 1024)
        atomicAdd(&hist[edge_at(ei, E + i, is64) >> 7], 1);
    __syncthreads();
    for (int b = threadIdx.x; b < nbkt; b += 1024)
        if (hist[b]) atomicAdd(&bkt_cnt[b], hist[b]);
}

__global__ __launch_bounds__(512) void k_bscan(const int* __restrict__ bkt_cnt,
                                               int* __restrict__ bkt_base,
                                               int* __restrict__ bkt_cur, int nbkt) {
    __shared__ int sm[512];
    int t = threadIdx.x;
    int e0 = (2 * t < nbkt) ? bkt_cnt[2 * t] : 0;
    int e1 = (2 * t + 1 < nbkt) ? bkt_cnt[2 * t + 1] : 0;
    int pv = e0 + e1;
    sm[t] = pv;
    __syncthreads();
    for (int o = 1; o < 512; o <<= 1) {
        int x = (t >= o) ? sm[t - o] : 0;
        __syncthreads();
        sm[t] += x;
        __syncthreads();
    }
    int base = sm[t] - pv;
    if (2 * t < nbkt)     { bkt_base[2 * t] = base;          bkt_cur[2 * t] = base; }
    if (2 * t + 1 < nbkt) { bkt_base[2 * t + 1] = base + e0; bkt_cur[2 * t + 1] = base + e0; }
}

__global__ __launch_bounds__(1024) void k_bin_scatter(const int* __restrict__ ei, long long E,
                                                      const int* __restrict__ flag,
                                                      int* __restrict__ bkt_cur,
                                                      unsigned* __restrict__ packed, int nbkt) {
    __shared__ int hist[MAXBKT];
    int is64 = *flag;
    for (int i = threadIdx.x; i < nbkt; i += 1024) hist[i] = 0;
    __syncthreads();
    long long chunk = (E + gridDim.x - 1) / gridDim.x;
    long long lo = (long long)blockIdx.x * chunk;
    long long hi = lo + chunk; if (hi > E) hi = E;
    for (long long i = lo + threadIdx.x; i < hi; i += 1024)
        atomicAdd(&hist[edge_at(ei, E + i, is64) >> 7], 1);
    __syncthreads();
    for (int b = threadIdx.x; b < nbkt; b += 1024) {
        int c = hist[b];
        hist[b] = c ? atomicAdd(&bkt_cur[b], c) : 0;
    }
    __syncthreads();
    for (long long i = lo + threadIdx.x; i < hi; i += 1024) {
        int s = edge_at(ei, i, is64);
        int d = edge_at(ei, E + i, is64);
        int slot = atomicAdd(&hist[d >> 7], 1);
        packed[slot] = (unsigned)s | ((unsigned)(d & (NPB - 1)) << 20);
    }
}

// ---------------- per-bucket counting sort -> node-level CSR ---------------
__global__ __launch_bounds__(256) void k_bucket_csr(const unsigned* __restrict__ packed,
                                                    const int* __restrict__ bkt_base,
                                                    const int* __restrict__ bkt_cnt,
                                                    int* __restrict__ csr_src,
                                                    int* __restrict__ ptr,
                                                    int* __restrict__ cnt,
                                                    float* __restrict__ dinv, int n) {
    __shared__ int hist[NPB];
    __shared__ int off[NPB];
    if (threadIdx.x < NPB) hist[threadIdx.x] = 0;
    __syncthreads();
    int base = bkt_base[blockIdx.x], m = bkt_cnt[blockIdx.x];
    for (int i = threadIdx.x; i < m; i += 256)
        atomicAdd(&hist[packed[base + i] >> 20], 1);
    __syncthreads();
    if (threadIdx.x < NPB) off[threadIdx.x] = hist[threadIdx.x];
    __syncthreads();
    for (int o = 1; o < NPB; o <<= 1) {
        int v = 0;
        if (threadIdx.x < NPB && threadIdx.x >= o) v = off[threadIdx.x - o];
        __syncthreads();
        if (threadIdx.x < NPB) off[threadIdx.x] += v;
        __syncthreads();
    }
    int node = blockIdx.x * NPB + threadIdx.x;
    if (threadIdx.x < NPB) {
        int exc = off[threadIdx.x] - hist[threadIdx.x];
        if (node < n) {
            ptr[node]  = base + exc;
            cnt[node]  = hist[threadIdx.x];
            dinv[node] = rsqrtf((float)hist[threadIdx.x] + 1.0f);
        }
        hist[threadIdx.x] = exc;
    }
    __syncthreads();
    for (int i = threadIdx.x; i < m; i += 256) {
        unsigned w = packed[base + i];
        int r = atomicAdd(&hist[w >> 20], 1);
        csr_src[base + r] = (int)(w & 0xFFFFF);
    }
}

// ---------------- gemm1: h1b = bf16((x @ W1) * dinv)  [n,256]x[256,32] -----
// Round-12 structure (W via LDS broadcast — proven 70us; scalar path rejected
// rounds 6/13) + M_r=2 register blocking: each thread owns 2 nodes x 8 o
// (16 STATIC acc scalars), x read as ds_read_b128 (4 k/issue). LDS issues
// per 64 FMA: 10 (vs round-12's 24) -> ~2.4x less LDS-issue pressure.
#define G1_NODES 128
#define FMA2x8(xv0, xv1, wlo, whi) \
    a0 = fmaf(xv0, wlo.x, a0); a1 = fmaf(xv0, wlo.y, a1); \
    a2 = fmaf(xv0, wlo.z, a2); a3 = fmaf(xv0, wlo.w, a3); \
    a4 = fmaf(xv0, whi.x, a4); a5 = fmaf(xv0, whi.y, a5); \
    a6 = fmaf(xv0, whi.z, a6); a7 = fmaf(xv0, whi.w, a7); \
    b0 = fmaf(xv1, wlo.x, b0); b1 = fmaf(xv1, wlo.y, b1); \
    b2 = fmaf(xv1, wlo.z, b2); b3 = fmaf(xv1, wlo.w, b3); \
    b4 = fmaf(xv1, whi.x, b4); b5 = fmaf(xv1, whi.y, b5); \
    b6 = fmaf(xv1, whi.z, b6); b7 = fmaf(xv1, whi.w, b7);

__global__ __launch_bounds__(256) void k_gemm1(const float* __restrict__ x,
                                               const float* __restrict__ W1,
                                               const float* __restrict__ dinv,
                                               unsigned* __restrict__ h1b, int n) {
    __shared__ float xs[G1_NODES][36];   // 18.4 KB; rows 16B-aligned
    __shared__ float wl[32][36];         // 4.6 KB
    const int t = threadIdx.x;
    const int lane = t & 63;
    const int oq0 = (t >> 6) * 8;        // wave's o-octet base
    const long long nb0 = (long long)blockIdx.x * G1_NODES;
    const long long node0 = nb0 + lane;
    const long long node1 = node0 + 64;

    float a0 = 0.f, a1 = 0.f, a2 = 0.f, a3 = 0.f;
    float a4 = 0.f, a5 = 0.f, a6 = 0.f, a7 = 0.f;
    float b0 = 0.f, b1 = 0.f, b2 = 0.f, b3 = 0.f;
    float b4 = 0.f, b5 = 0.f, b6 = 0.f, b7 = 0.f;

    for (int c = 0; c < IN_C / 32; ++c) {          // 8 chunks of 32 k
        const int k0 = c * 32;
        // stage x[128][32]: 1024 float4, 4/thread; lanes 0..7 = one 128B row
#pragma unroll
        for (int j = 0; j < 4; ++j) {
            int f = j * 256 + t;
            int row = f >> 3, c4 = f & 7;
            long long nd = nb0 + row;
            float4 v = make_float4(0.f, 0.f, 0.f, 0.f);
            if (nd < n) v = *(const float4*)(x + nd * IN_C + k0 + c4 * 4);
            *(float4*)&xs[row][c4 * 4] = v;
        }
        // stage W chunk [32 k][32 o]: 1 float4/thread
        {
            int kk = t >> 3, o4 = (t & 7) * 4;
            float4 w = *(const float4*)(W1 + (long long)(k0 + kk) * HIDC + o4);
            *(float4*)&wl[kk][o4] = w;
        }
        __syncthreads();
#pragma unroll
        for (int g = 0; g < 8; ++g) {              // 4 k per group
            const int kb = g * 4;
            float4 xa = *(const float4*)&xs[lane][kb];        // node0, 4 k
            float4 xb = *(const float4*)&xs[lane + 64][kb];   // node1, 4 k
            float4 wl0 = *(const float4*)&wl[kb + 0][oq0];
            float4 wh0 = *(const float4*)&wl[kb + 0][oq0 + 4];
            float4 wl1 = *(const float4*)&wl[kb + 1][oq0];
            float4 wh1 = *(const float4*)&wl[kb + 1][oq0 + 4];
            float4 wl2 = *(const float4*)&wl[kb + 2][oq0];
            float4 wh2 = *(const float4*)&wl[kb + 2][oq0 + 4];
            float4 wl3 = *(const float4*)&wl[kb + 3][oq0];
            float4 wh3 = *(const float4*)&wl[kb + 3][oq0 + 4];
            FMA2x8(xa.x, xb.x, wl0, wh0)
            FMA2x8(xa.y, xb.y, wl1, wh1)
            FMA2x8(xa.z, xb.z, wl2, wh2)
            FMA2x8(xa.w, xb.w, wl3, wh3)
        }
        __syncthreads();
    }
    if (node0 < n) {
        float di = dinv[node0];
        uint4 p;
        p.x = bf16pair(a0 * di, a1 * di);
        p.y = bf16pair(a2 * di, a3 * di);
        p.z = bf16pair(a4 * di, a5 * di);
        p.w = bf16pair(a6 * di, a7 * di);
        *(uint4*)(h1b + node0 * (HIDC / 2) + oq0 / 2) = p;
    }
    if (node1 < n) {
        float di = dinv[node1];
        uint4 p;
        p.x = bf16pair(b0 * di, b1 * di);
        p.y = bf16pair(b2 * di, b3 * di);
        p.z = bf16pair(b4 * di, b5 * di);
        p.w = bf16pair(b6 * di, b7 * di);
        *(uint4*)(h1b + node1 * (HIDC / 2) + oq0 / 2) = p;
    }
}

// ---------------- layer-1 pull aggregation (bf16 gathers) ------------------
__global__ __launch_bounds__(256) void k_agg1csr(const int* __restrict__ ptr,
                                                 const int* __restrict__ cnt,
                                                 const int* __restrict__ csr_src,
                                                 const float* __restrict__ dinv,
                                                 const unsigned* __restrict__ h1b,
                                                 const float* __restrict__ b1,
                                                 float* __restrict__ h1r, int n) {
    long long g = (long long)blockIdx.x * blockDim.x + threadIdx.x;
    int node = (int)(g >> 4);
    int cp = (int)(g & 15);              // channel pair
    if (node >= n) return;
    unsigned us = h1b[(long long)node * 16 + cp];
    float accL = bf16lo(us), accH = bf16hi(us);   // self term (pre-scaled)
    int st = ptr[node], deg = cnt[node];
    int j = 0;
    for (; j + 3 < deg; j += 4) {
        int s0 = csr_src[st + j], s1 = csr_src[st + j + 1];
        int s2 = csr_src[st + j + 2], s3 = csr_src[st + j + 3];
        unsigned u0 = h1b[(long long)s0 * 16 + cp];
        unsigned u1 = h1b[(long long)s1 * 16 + cp];
        unsigned u2 = h1b[(long long)s2 * 16 + cp];
        unsigned u3 = h1b[(long long)s3 * 16 + cp];
        accL += (bf16lo(u0) + bf16lo(u1)) + (bf16lo(u2) + bf16lo(u3));
        accH += (bf16hi(u0) + bf16hi(u1)) + (bf16hi(u2) + bf16hi(u3));
    }
    for (; j < deg; ++j) {
        unsigned u = h1b[(long long)csr_src[st + j] * 16 + cp];
        accL += bf16lo(u); accH += bf16hi(u);
    }
    float di = dinv[node];
    float vL = accL * di + b1[2 * cp];
    float vH = accH * di + b1[2 * cp + 1];
    *(float2*)(h1r + (long long)node * HIDC + 2 * cp) =
        make_float2(vL > 0.f ? vL : 0.f, vH > 0.f ? vH : 0.f);
}

// ---------------- gemm2: h2b = bf16((h1r @ W2) * dinv) ---------------------
__global__ __launch_bounds__(256) void k_gemm2(const float* __restrict__ h1,
                                               const float* __restrict__ W2,
                                               const float* __restrict__ dinv,
                                               unsigned* __restrict__ h2b, int n) {
    const int t = threadIdx.x;
    const int oq = (t & 3) * 4;
    const long long node = (long long)blockIdx.x * 64 + (t >> 2);
    if (node >= n) return;
    const float* __restrict__ xp = h1 + node * HIDC;
    float a0 = 0.f, a1 = 0.f, a2 = 0.f, a3 = 0.f;
#pragma unroll
    for (int k0 = 0; k0 < HIDC; k0 += 8) {
        float4 xv0 = *(const float4*)(xp + k0);
        float4 xv1 = *(const float4*)(xp + k0 + 4);
        const float* __restrict__ wp = W2 + (long long)k0 * OUTC + oq;
        float4 w0 = *(const float4*)(wp + 0 * OUTC);
        float4 w1 = *(const float4*)(wp + 1 * OUTC);
        float4 w2 = *(const float4*)(wp + 2 * OUTC);
        float4 w3 = *(const float4*)(wp + 3 * OUTC);
        float4 w4 = *(const float4*)(wp + 4 * OUTC);
        float4 w5 = *(const float4*)(wp + 5 * OUTC);
        float4 w6 = *(const float4*)(wp + 6 * OUTC);
        float4 w7 = *(const float4*)(wp + 7 * OUTC);
        a0 = fmaf(xv0.x, w0.x, a0); a1 = fmaf(xv0.x, w0.y, a1);
        a2 = fmaf(xv0.x, w0.z, a2); a3 = fmaf(xv0.x, w0.w, a3);
        a0 = fmaf(xv0.y, w1.x, a0); a1 = fmaf(xv0.y, w1.y, a1);
        a2 = fmaf(xv0.y, w1.z, a2); a3 = fmaf(xv0.y, w1.w, a3);
        a0 = fmaf(xv0.z, w2.x, a0); a1 = fmaf(xv0.z, w2.y, a1);
        a2 = fmaf(xv0.z, w2.z, a2); a3 = fmaf(xv0.z, w2.w, a3);
        a0 = fmaf(xv0.w, w3.x, a0); a1 = fmaf(xv0.w, w3.y, a1);
        a2 = fmaf(xv0.w, w3.z, a2); a3 = fmaf(xv0.w, w3.w, a3);
        a0 = fmaf(xv1.x, w4.x, a0); a1 = fmaf(xv1.x, w4.y, a1);
        a2 = fmaf(xv1.x, w4.z, a2); a3 = fmaf(xv1.x, w4.w, a3);
        a0 = fmaf(xv1.y, w5.x, a0); a1 = fmaf(xv1.y, w5.y, a1);
        a2 = fmaf(xv1.y, w5.z, a2); a3 = fmaf(xv1.y, w5.w, a3);
        a0 = fmaf(xv1.z, w6.x, a0); a1 = fmaf(xv1.z, w6.y, a1);
        a2 = fmaf(xv1.z, w6.z, a2); a3 = fmaf(xv1.z, w6.w, a3);
        a0 = fmaf(xv1.w, w7.x, a0); a1 = fmaf(xv1.w, w7.y, a1);
        a2 = fmaf(xv1.w, w7.z, a2); a3 = fmaf(xv1.w, w7.w, a3);
    }
    float di = dinv[node];
    uint2 p;
    p.x = bf16pair(a0 * di, a1 * di);
    p.y = bf16pair(a2 * di, a3 * di);
    *(uint2*)(h2b + node * (OUTC / 2) + oq / 2) = p;
}

// ---------------- layer-2 pull aggregation (bf16 gathers) -> d_out ---------
__global__ __launch_bounds__(256) void k_agg2csr(const int* __restrict__ ptr,
                                                 const int* __restrict__ cnt,
                                                 const int* __restrict__ csr_src,
                                                 const float* __restrict__ dinv,
                                                 const unsigned* __restrict__ h2b,
                                                 const float* __restrict__ b2,
                                                 float* __restrict__ out, int n) {
    long long g = (long long)blockIdx.x * blockDim.x + threadIdx.x;
    int node = (int)(g >> 3);
    int cp = (int)(g & 7);
    if (node >= n) return;
    unsigned us = h2b[(long long)node * 8 + cp];
    float accL = bf16lo(us), accH = bf16hi(us);
    int st = ptr[node], deg = cnt[node];
    int j = 0;
    for (; j + 3 < deg; j += 4) {
        int s0 = csr_src[st + j], s1 = csr_src[st + j + 1];
        int s2 = csr_src[st + j + 2], s3 = csr_src[st + j + 3];
        unsigned u0 = h2b[(long long)s0 * 8 + cp];
        unsigned u1 = h2b[(long long)s1 * 8 + cp];
        unsigned u2 = h2b[(long long)s2 * 8 + cp];
        unsigned u3 = h2b[(long long)s3 * 8 + cp];
        accL += (bf16lo(u0) + bf16lo(u1)) + (bf16lo(u2) + bf16lo(u3));
        accH += (bf16hi(u0) + bf16hi(u1)) + (bf16hi(u2) + bf16hi(u3));
    }
    for (; j < deg; ++j) {
        unsigned u = h2b[(long long)csr_src[st + j] * 8 + cp];
        accL += bf16lo(u); accH += bf16hi(u);
    }
    float di = dinv[node];
    *(float2*)(out + (long long)node * OUTC + 2 * cp) =
        make_float2(accL * di + b2[2 * cp], accH * di + b2[2 * cp + 1]);
}

extern "C" void kernel_launch(void* const* d_in, const int* in_sizes, int n_in,
                              void* d_out, int out_size, void* d_ws, size_t ws_size,
                              hipStream_t stream) {
    const float* x  = (const float*)d_in[0];
    const int*   ei = (const int*)d_in[1];
    const float* W1 = (const float*)d_in[2];
    const float* b1 = (const float*)d_in[3];
    const float* W2 = (const float*)d_in[4];
    const float* b2 = (const float*)d_in[5];
    const int n = in_sizes[0] / IN_C;            // 100000
    const long long E = in_sizes[1] / 2;         // 3200000
    float* out = (float*)d_out;

    const int nbkt = (n + NPB - 1) / NPB;        // 782

    char* ws = (char*)d_ws;
    size_t off = 0;
    auto alloc = [&](size_t bytes) { void* p = ws + off; off += (bytes + 255) & ~(size_t)255; return p; };
    int*      flag     = (int*)alloc(256);
    int*      bkt_cnt  = (int*)alloc((size_t)MAXBKT * 4);
    int*      bkt_base = (int*)alloc((size_t)MAXBKT * 4);
    int*      bkt_cur  = (int*)alloc((size_t)MAXBKT * 4);
    float*    dinv     = (float*)alloc((size_t)n * 4);
    int*      cnt      = (int*)alloc((size_t)n * 4);
    int*      ptr      = (int*)alloc((size_t)n * 4);
    unsigned* packed   = (unsigned*)alloc((size_t)E * 4);
    int*      csr_src  = (int*)alloc((size_t)E * 4);
    unsigned* h1b      = (unsigned*)alloc((size_t)n * (HIDC / 2) * 4);  // bf16 [n][32]
    float*    h1r      = (float*)alloc((size_t)n * HIDC * 4);
    unsigned* h2b      = (unsigned*)alloc((size_t)n * (OUTC / 2) * 4);  // bf16 [n][16]

    hipMemsetAsync(bkt_cnt, 0, (size_t)nbkt * 4, stream);

    k_detect<<<1, 256, 0, stream>>>(ei, flag);
    k_bin_count<<<256, 1024, 0, stream>>>(ei, E, flag, bkt_cnt, nbkt);
    k_bscan<<<1, 512, 0, stream>>>(bkt_cnt, bkt_base, bkt_cur, nbkt);
    k_bin_scatter<<<256, 1024, 0, stream>>>(ei, E, flag, bkt_cur, packed, nbkt);
    k_bucket_csr<<<nbkt, 256, 0, stream>>>(packed, bkt_base, bkt_cnt, csr_src, ptr, cnt, dinv, n);

    k_gemm1<<<(n + G1_NODES - 1) / G1_NODES, 256, 0, stream>>>(x, W1, dinv, h1b, n);
    k_agg1csr<<<(int)(((long long)n * 16 + 255) / 256), 256, 0, stream>>>(
        ptr, cnt, csr_src, dinv, h1b, b1, h1r, n);
    k_gemm2<<<(n + 63) / 64, 256, 0, stream>>>(h1r, W2, dinv, h2b, n);
    k_agg2csr<<<(int)(((long long)n * 8 + 255) / 256), 256, 0, stream>>>(
        ptr, cnt, csr_src, dinv, h2b, b2, out, n);
}

// Round 15
// 185.229 us; speedup vs baseline: 1.3972x; 1.0890x over previous
//
#include <hip/hip_runtime.h>

#define IN_C 256
#define HIDC 32
#define OUTC 16
#define NPB  256          // nodes per bucket (d_local = 8 bits)
#define MAXBKT 800

typedef __attribute__((ext_vector_type(8))) short short8;
typedef __attribute__((ext_vector_type(4))) float f32x4;
union S8U4 { short8 s; unsigned u[4]; };

// ---------------- bf16 helpers ---------------------------------------------
__device__ __forceinline__ unsigned bf16pair(float a, float b) {   // RNE pack
    unsigned ua = __float_as_uint(a); ua += 0x7FFF + ((ua >> 16) & 1);
    unsigned ub = __float_as_uint(b); ub += 0x7FFF + ((ub >> 16) & 1);
    return (ua >> 16) | (ub & 0xFFFF0000u);
}
__device__ __forceinline__ float bf16lo(unsigned u) { return __uint_as_float(u << 16); }
__device__ __forceinline__ float bf16hi(unsigned u) { return __uint_as_float(u & 0xFFFF0000u); }
__device__ __forceinline__ unsigned rbf(float a) {                 // bf16 bits, RNE
    unsigned u = __float_as_uint(a);
    u += 0x7FFF + ((u >> 16) & 1);
    return u >> 16;
}
// split 8 f32 -> hi/lo bf16x8 (x = hi + lo to ~2^-17 rel)
__device__ __forceinline__ void split8(const float* xf, short8& hi, short8& lo) {
    S8U4 H, L;
#pragma unroll
    for (int i = 0; i < 4; ++i) {
        float a = xf[2 * i], b = xf[2 * i + 1];
        unsigned ha = rbf(a), hb = rbf(b);
        float ra = a - __uint_as_float(ha << 16);
        float rb = b - __uint_as_float(hb << 16);
        H.u[i] = ha | (hb << 16);
        L.u[i] = rbf(ra) | (rbf(rb) << 16);
    }
    hi = H.s; lo = L.s;
}

// ---------------- edge index loader (handles int32 or int64 storage) -------
__device__ __forceinline__ int edge_at(const int* __restrict__ ei, long long idx, int is64) {
    return is64 ? ei[idx << 1] : ei[idx];
}

__global__ void k_detect(const int* __restrict__ ei, int* __restrict__ flag) {
    __shared__ int nz;
    if (threadIdx.x == 0) nz = 0;
    __syncthreads();
    if (ei[2 * threadIdx.x + 1] != 0) atomicOr(&nz, 1);
    __syncthreads();
    if (threadIdx.x == 0) *flag = (nz == 0) ? 1 : 0;
}

// ---------------- bucket binning (256 blocks x 1024 thr) -------------------
__global__ __launch_bounds__(1024) void k_bin_count(const int* __restrict__ ei, long long E,
                                                    const int* __restrict__ flag,
                                                    int* __restrict__ bkt_cnt, int nbkt) {
    __shared__ int hist[MAXBKT];
    int is64 = *flag;
    for (int i = threadIdx.x; i < nbkt; i += 1024) hist[i] = 0;
    __syncthreads();
    long long chunk = (E + gridDim.x - 1) / gridDim.x;
    long long lo = (long long)blockIdx.x * chunk;
    long long hi = lo + chunk; if (hi > E) hi = E;
    for (long long i = lo + threadIdx.x; i < hi; i += 1024)
        atomicAdd(&hist[edge_at(ei, E + i, is64) >> 8], 1);
    __syncthreads();
    for (int b = threadIdx.x; b < nbkt; b += 1024)
        if (hist[b]) atomicAdd(&bkt_cnt[b], hist[b]);
}

__global__ __launch_bounds__(512) void k_bscan(const int* __restrict__ bkt_cnt,
                                               int* __restrict__ bkt_base,
                                               int* __restrict__ bkt_cur, int nbkt) {
    __shared__ int sm[512];
    int t = threadIdx.x;
    int e0 = (2 * t < nbkt) ? bkt_cnt[2 * t] : 0;
    int e1 = (2 * t + 1 < nbkt) ? bkt_cnt[2 * t + 1] : 0;
    int pv = e0 + e1;
    sm[t] = pv;
    __syncthreads();
    for (int o = 1; o < 512; o <<= 1) {
        int x = (t >= o) ? sm[t - o] : 0;
        __syncthreads();
        sm[t] += x;
        __syncthreads();
    }
    int base = sm[t] - pv;
    if (2 * t < nbkt)     { bkt_base[2 * t] = base;          bkt_cur[2 * t] = base; }
    if (2 * t + 1 < nbkt) { bkt_base[2 * t + 1] = base + e0; bkt_cur[2 * t + 1] = base + e0; }
}

__global__ __launch_bounds__(1024) void k_bin_scatter(const int* __restrict__ ei, long long E,
                                                      const int* __restrict__ flag,
                                                      int* __restrict__ bkt_cur,
                                                      unsigned* __restrict__ packed, int nbkt) {
    __shared__ int hist[MAXBKT];
    int is64 = *flag;
    for (int i = threadIdx.x; i < nbkt; i += 1024) hist[i] = 0;
    __syncthreads();
    long long chunk = (E + gridDim.x - 1) / gridDim.x;
    long long lo = (long long)blockIdx.x * chunk;
    long long hi = lo + chunk; if (hi > E) hi = E;
    for (long long i = lo + threadIdx.x; i < hi; i += 1024)
        atomicAdd(&hist[edge_at(ei, E + i, is64) >> 8], 1);
    __syncthreads();
    for (int b = threadIdx.x; b < nbkt; b += 1024) {
        int c = hist[b];
        hist[b] = c ? atomicAdd(&bkt_cur[b], c) : 0;
    }
    __syncthreads();
    for (long long i = lo + threadIdx.x; i < hi; i += 1024) {
        int s = edge_at(ei, i, is64);
        int d = edge_at(ei, E + i, is64);
        int slot = atomicAdd(&hist[d >> 8], 1);
        packed[slot] = (unsigned)s | ((unsigned)(d & (NPB - 1)) << 20);
    }
}

// ---------------- per-bucket counting sort -> node-level CSR ---------------
__global__ __launch_bounds__(256) void k_bucket_csr(const unsigned* __restrict__ packed,
                                                    const int* __restrict__ bkt_base,
                                                    const int* __restrict__ bkt_cnt,
                                                    int* __restrict__ csr_src,
                                                    int* __restrict__ ptr,
                                                    int* __restrict__ cnt,
                                                    float* __restrict__ dinv, int n) {
    __shared__ int hist[NPB];
    __shared__ int off[NPB];
    hist[threadIdx.x] = 0;
    __syncthreads();
    int base = bkt_base[blockIdx.x], m = bkt_cnt[blockIdx.x];
    for (int i = threadIdx.x; i < m; i += 256)
        atomicAdd(&hist[packed[base + i] >> 20], 1);
    __syncthreads();
    off[threadIdx.x] = hist[threadIdx.x];
    __syncthreads();
    for (int o = 1; o < NPB; o <<= 1) {
        int v = (threadIdx.x >= o) ? off[threadIdx.x - o] : 0;
        __syncthreads();
        off[threadIdx.x] += v;
        __syncthreads();
    }
    int node = blockIdx.x * NPB + threadIdx.x;
    {
        int exc = off[threadIdx.x] - hist[threadIdx.x];
        if (node < n) {
            ptr[node]  = base + exc;
            cnt[node]  = hist[threadIdx.x];
            dinv[node] = rsqrtf((float)hist[threadIdx.x] + 1.0f);
        }
        hist[threadIdx.x] = exc;
    }
    __syncthreads();
    for (int i = threadIdx.x; i < m; i += 256) {
        unsigned w = packed[base + i];
        int r = atomicAdd(&hist[w >> 20], 1);
        csr_src[base + r] = (int)(w & 0xFFFFF);
    }
}

// ---------------- W1 fragment pre-build for MFMA ---------------------------
// wf entry idx = s*256 + tile*128 + part*64 + lane; 8 bf16 each:
// W1[s*32 + (lane>>4)*8 + j][tile*16 + (lane&15)], part 0=hi 1=lo.
__global__ void k_wfrag(const float* __restrict__ W1, unsigned short* __restrict__ wf) {
    int idx = blockIdx.x * 256 + threadIdx.x;
    if (idx >= 8 * 2 * 2 * 64) return;
    int lane = idx & 63;
    int part = (idx >> 6) & 1;
    int tile = (idx >> 7) & 1;
    int s    = idx >> 8;
    int col = tile * 16 + (lane & 15);
    int k0  = s * 32 + (lane >> 4) * 8;
#pragma unroll
    for (int j = 0; j < 8; ++j) {
        float v = W1[(long long)(k0 + j) * HIDC + col];
        unsigned h = rbf(v);
        float r = v - __uint_as_float(h << 16);
        wf[(long long)idx * 8 + j] = (unsigned short)(part == 0 ? h : rbf(r));
    }
}

// ---------------- gemm1 via MFMA: h1b = bf16((x @ W1) * dinv) --------------
// Round-14 lesson: f32-FMA-through-LDS is LDS-issue bound (~55us floor).
// MFMA 16x16x32 bf16 with split precision: xh*Wh + xh*Wl + xl*Wh (~2^-17).
// A-frags straight from global x (16 rows x 128B contiguous per kstep),
// B-frags from prebuilt wf (L1-hot, 16B/lane). No LDS, no barriers.
__global__ __launch_bounds__(256) void k_gemm1(const float* __restrict__ x,
                                               const unsigned short* __restrict__ wf,
                                               const float* __restrict__ dinv,
                                               unsigned short* __restrict__ h1b_us, int n) {
    const int t = threadIdx.x;
    const int l = t & 63;
    const int w = t >> 6;
    const long long nb0 = (long long)blockIdx.x * 64 + w * 16;   // wave's 16 nodes
    const int arow = l & 15;
    const int kg = l >> 4;                 // k-chunk 0..3
    const long long nodeA = nb0 + arow;
    const bool loadA = nodeA < n;
    f32x4 acc0 = {0.f, 0.f, 0.f, 0.f}, acc1 = {0.f, 0.f, 0.f, 0.f};

#pragma unroll
    for (int s = 0; s < 8; ++s) {
        float xf[8];
        if (loadA) {
            float4 v0 = *(const float4*)(x + nodeA * IN_C + s * 32 + kg * 8);
            float4 v1 = *(const float4*)(x + nodeA * IN_C + s * 32 + kg * 8 + 4);
            xf[0] = v0.x; xf[1] = v0.y; xf[2] = v0.z; xf[3] = v0.w;
            xf[4] = v1.x; xf[5] = v1.y; xf[6] = v1.z; xf[7] = v1.w;
        } else {
#pragma unroll
            for (int j = 0; j < 8; ++j) xf[j] = 0.f;
        }
        short8 ah, al;
        split8(xf, ah, al);
        const unsigned short* base = wf + ((long long)(s * 4) * 64 + l) * 8;
        short8 bh0 = *(const short8*)(base);
        short8 bl0 = *(const short8*)(base + 64 * 8);
        short8 bh1 = *(const short8*)(base + 2 * 64 * 8);
        short8 bl1 = *(const short8*)(base + 3 * 64 * 8);
        acc0 = __builtin_amdgcn_mfma_f32_16x16x32_bf16(ah, bh0, acc0, 0, 0, 0);
        acc0 = __builtin_amdgcn_mfma_f32_16x16x32_bf16(ah, bl0, acc0, 0, 0, 0);
        acc0 = __builtin_amdgcn_mfma_f32_16x16x32_bf16(al, bh0, acc0, 0, 0, 0);
        acc1 = __builtin_amdgcn_mfma_f32_16x16x32_bf16(ah, bh1, acc1, 0, 0, 0);
        acc1 = __builtin_amdgcn_mfma_f32_16x16x32_bf16(ah, bl1, acc1, 0, 0, 0);
        acc1 = __builtin_amdgcn_mfma_f32_16x16x32_bf16(al, bh1, acc1, 0, 0, 0);
    }
    // D layout (m89-verified): row = (l>>4)*4 + r, col = l&15
#pragma unroll
    for (int r = 0; r < 4; ++r) {
        long long nd = nb0 + (l >> 4) * 4 + r;
        if (nd < n) {
            float di = dinv[nd];
            h1b_us[nd * 32 + (l & 15)]      = (unsigned short)rbf(acc0[r] * di);
            h1b_us[nd * 32 + 16 + (l & 15)] = (unsigned short)rbf(acc1[r] * di);
        }
    }
}

// ---------------- layer-1 pull aggregation (bf16 gathers) ------------------
__global__ __launch_bounds__(256) void k_agg1csr(const int* __restrict__ ptr,
                                                 const int* __restrict__ cnt,
                                                 const int* __restrict__ csr_src,
                                                 const float* __restrict__ dinv,
                                                 const unsigned* __restrict__ h1b,
                                                 const float* __restrict__ b1,
                                                 float* __restrict__ h1r, int n) {
    long long g = (long long)blockIdx.x * blockDim.x + threadIdx.x;
    int node = (int)(g >> 4);
    int cp = (int)(g & 15);
    if (node >= n) return;
    unsigned us = h1b[(long long)node * 16 + cp];
    float accL = bf16lo(us), accH = bf16hi(us);
    int st = ptr[node], deg = cnt[node];
    int j = 0;
    for (; j + 3 < deg; j += 4) {
        int s0 = csr_src[st + j], s1 = csr_src[st + j + 1];
        int s2 = csr_src[st + j + 2], s3 = csr_src[st + j + 3];
        unsigned u0 = h1b[(long long)s0 * 16 + cp];
        unsigned u1 = h1b[(long long)s1 * 16 + cp];
        unsigned u2 = h1b[(long long)s2 * 16 + cp];
        unsigned u3 = h1b[(long long)s3 * 16 + cp];
        accL += (bf16lo(u0) + bf16lo(u1)) + (bf16lo(u2) + bf16lo(u3));
        accH += (bf16hi(u0) + bf16hi(u1)) + (bf16hi(u2) + bf16hi(u3));
    }
    for (; j < deg; ++j) {
        unsigned u = h1b[(long long)csr_src[st + j] * 16 + cp];
        accL += bf16lo(u); accH += bf16hi(u);
    }
    float di = dinv[node];
    float vL = accL * di + b1[2 * cp];
    float vH = accH * di + b1[2 * cp + 1];
    *(float2*)(h1r + (long long)node * HIDC + 2 * cp) =
        make_float2(vL > 0.f ? vL : 0.f, vH > 0.f ? vH : 0.f);
}

// ---------------- gemm2: h2b = bf16((h1r @ W2) * dinv) ---------------------
__global__ __launch_bounds__(256) void k_gemm2(const float* __restrict__ h1,
                                               const float* __restrict__ W2,
                                               const float* __restrict__ dinv,
                                               unsigned* __restrict__ h2b, int n) {
    const int t = threadIdx.x;
    const int oq = (t & 3) * 4;
    const long long node = (long long)blockIdx.x * 64 + (t >> 2);
    if (node >= n) return;
    const float* __restrict__ xp = h1 + node * HIDC;
    float a0 = 0.f, a1 = 0.f, a2 = 0.f, a3 = 0.f;
#pragma unroll
    for (int k0 = 0; k0 < HIDC; k0 += 8) {
        float4 xv0 = *(const float4*)(xp + k0);
        float4 xv1 = *(const float4*)(xp + k0 + 4);
        const float* __restrict__ wp = W2 + (long long)k0 * OUTC + oq;
        float4 w0 = *(const float4*)(wp + 0 * OUTC);
        float4 w1 = *(const float4*)(wp + 1 * OUTC);
        float4 w2 = *(const float4*)(wp + 2 * OUTC);
        float4 w3 = *(const float4*)(wp + 3 * OUTC);
        float4 w4 = *(const float4*)(wp + 4 * OUTC);
        float4 w5 = *(const float4*)(wp + 5 * OUTC);
        float4 w6 = *(const float4*)(wp + 6 * OUTC);
        float4 w7 = *(const float4*)(wp + 7 * OUTC);
        a0 = fmaf(xv0.x, w0.x, a0); a1 = fmaf(xv0.x, w0.y, a1);
        a2 = fmaf(xv0.x, w0.z, a2); a3 = fmaf(xv0.x, w0.w, a3);
        a0 = fmaf(xv0.y, w1.x, a0); a1 = fmaf(xv0.y, w1.y, a1);
        a2 = fmaf(xv0.y, w1.z, a2); a3 = fmaf(xv0.y, w1.w, a3);
        a0 = fmaf(xv0.z, w2.x, a0); a1 = fmaf(xv0.z, w2.y, a1);
        a2 = fmaf(xv0.z, w2.z, a2); a3 = fmaf(xv0.z, w2.w, a3);
        a0 = fmaf(xv0.w, w3.x, a0); a1 = fmaf(xv0.w, w3.y, a1);
        a2 = fmaf(xv0.w, w3.z, a2); a3 = fmaf(xv0.w, w3.w, a3);
        a0 = fmaf(xv1.x, w4.x, a0); a1 = fmaf(xv1.x, w4.y, a1);
        a2 = fmaf(xv1.x, w4.z, a2); a3 = fmaf(xv1.x, w4.w, a3);
        a0 = fmaf(xv1.y, w5.x, a0); a1 = fmaf(xv1.y, w5.y, a1);
        a2 = fmaf(xv1.y, w5.z, a2); a3 = fmaf(xv1.y, w5.w, a3);
        a0 = fmaf(xv1.z, w6.x, a0); a1 = fmaf(xv1.z, w6.y, a1);
        a2 = fmaf(xv1.z, w6.z, a2); a3 = fmaf(xv1.z, w6.w, a3);
        a0 = fmaf(xv1.w, w7.x, a0); a1 = fmaf(xv1.w, w7.y, a1);
        a2 = fmaf(xv1.w, w7.z, a2); a3 = fmaf(xv1.w, w7.w, a3);
    }
    float di = dinv[node];
    uint2 p;
    p.x = bf16pair(a0 * di, a1 * di);
    p.y = bf16pair(a2 * di, a3 * di);
    *(uint2*)(h2b + node * (OUTC / 2) + oq / 2) = p;
}

// ---------------- layer-2 pull aggregation (bf16 gathers) -> d_out ---------
__global__ __launch_bounds__(256) void k_agg2csr(const int* __restrict__ ptr,
                                                 const int* __restrict__ cnt,
                                                 const int* __restrict__ csr_src,
                                                 const float* __restrict__ dinv,
                                                 const unsigned* __restrict__ h2b,
                                                 const float* __restrict__ b2,
                                                 float* __restrict__ out, int n) {
    long long g = (long long)blockIdx.x * blockDim.x + threadIdx.x;
    int node = (int)(g >> 3);
    int cp = (int)(g & 7);
    if (node >= n) return;
    unsigned us = h2b[(long long)node * 8 + cp];
    float accL = bf16lo(us), accH = bf16hi(us);
    int st = ptr[node], deg = cnt[node];
    int j = 0;
    for (; j + 3 < deg; j += 4) {
        int s0 = csr_src[st + j], s1 = csr_src[st + j + 1];
        int s2 = csr_src[st + j + 2], s3 = csr_src[st + j + 3];
        unsigned u0 = h2b[(long long)s0 * 8 + cp];
        unsigned u1 = h2b[(long long)s1 * 8 + cp];
        unsigned u2 = h2b[(long long)s2 * 8 + cp];
        unsigned u3 = h2b[(long long)s3 * 8 + cp];
        accL += (bf16lo(u0) + bf16lo(u1)) + (bf16lo(u2) + bf16lo(u3));
        accH += (bf16hi(u0) + bf16hi(u1)) + (bf16hi(u2) + bf16hi(u3));
    }
    for (; j < deg; ++j) {
        unsigned u = h2b[(long long)csr_src[st + j] * 8 + cp];
        accL += bf16lo(u); accH += bf16hi(u);
    }
    float di = dinv[node];
    *(float2*)(out + (long long)node * OUTC + 2 * cp) =
        make_float2(accL * di + b2[2 * cp], accH * di + b2[2 * cp + 1]);
}

extern "C" void kernel_launch(void* const* d_in, const int* in_sizes, int n_in,
                              void* d_out, int out_size, void* d_ws, size_t ws_size,
                              hipStream_t stream) {
    const float* x  = (const float*)d_in[0];
    const int*   ei = (const int*)d_in[1];
    const float* W1 = (const float*)d_in[2];
    const float* b1 = (const float*)d_in[3];
    const float* W2 = (const float*)d_in[4];
    const float* b2 = (const float*)d_in[5];
    const int n = in_sizes[0] / IN_C;            // 100000
    const long long E = in_sizes[1] / 2;         // 3200000
    float* out = (float*)d_out;

    const int nbkt = (n + NPB - 1) / NPB;        // 391

    char* ws = (char*)d_ws;
    size_t off = 0;
    auto alloc = [&](size_t bytes) { void* p = ws + off; off += (bytes + 255) & ~(size_t)255; return p; };
    int*      flag     = (int*)alloc(256);
    int*      bkt_cnt  = (int*)alloc((size_t)MAXBKT * 4);
    int*      bkt_base = (int*)alloc((size_t)MAXBKT * 4);
    int*      bkt_cur  = (int*)alloc((size_t)MAXBKT * 4);
    float*    dinv     = (float*)alloc((size_t)n * 4);
    int*      cnt      = (int*)alloc((size_t)n * 4);
    int*      ptr      = (int*)alloc((size_t)n * 4);
    unsigned* packed   = (unsigned*)alloc((size_t)E * 4);
    int*      csr_src  = (int*)alloc((size_t)E * 4);
    unsigned short* wf = (unsigned short*)alloc(8 * 2 * 2 * 64 * 8 * 2);  // 32 KB
    unsigned* h1b      = (unsigned*)alloc((size_t)n * (HIDC / 2) * 4);    // bf16 [n][32]
    float*    h1r      = (float*)alloc((size_t)n * HIDC * 4);
    unsigned* h2b      = (unsigned*)alloc((size_t)n * (OUTC / 2) * 4);    // bf16 [n][16]

    hipMemsetAsync(bkt_cnt, 0, (size_t)nbkt * 4, stream);

    k_detect<<<1, 256, 0, stream>>>(ei, flag);
    k_wfrag<<<8, 256, 0, stream>>>(W1, wf);
    k_bin_count<<<256, 1024, 0, stream>>>(ei, E, flag, bkt_cnt, nbkt);
    k_bscan<<<1, 512, 0, stream>>>(bkt_cnt, bkt_base, bkt_cur, nbkt);
    k_bin_scatter<<<256, 1024, 0, stream>>>(ei, E, flag, bkt_cur, packed, nbkt);
    k_bucket_csr<<<nbkt, NPB, 0, stream>>>(packed, bkt_base, bkt_cnt, csr_src, ptr, cnt, dinv, n);

    k_gemm1<<<(n + 63) / 64, 256, 0, stream>>>(x, wf, dinv, (unsigned short*)h1b, n);
    k_agg1csr<<<(int)(((long long)n * 16 + 255) / 256), 256, 0, stream>>>(
        ptr, cnt, csr_src, dinv, h1b, b1, h1r, n);
    k_gemm2<<<(n + 63) / 64, 256, 0, stream>>>(h1r, W2, dinv, h2b, n);
    k_agg2csr<<<(int)(((long long)n * 8 + 255) / 256), 256, 0, stream>>>(
        ptr, cnt, csr_src, dinv, h2b, b2, out, n);
}

// Round 16
// 182.010 us; speedup vs baseline: 1.4220x; 1.0177x over previous
//
#include <hip/hip_runtime.h>

#define IN_C 256
#define HIDC 32
#define OUTC 16
#define NPB  256          // nodes per bucket (d_local = 8 bits)
#define MAXBKT 800

typedef __attribute__((ext_vector_type(8))) short short8;
typedef __attribute__((ext_vector_type(4))) float f32x4;
union S8U4 { short8 s; unsigned u[4]; };

// ---------------- bf16 helpers ---------------------------------------------
__device__ __forceinline__ unsigned bf16pair(float a, float b) {   // RNE pack
    unsigned ua = __float_as_uint(a); ua += 0x7FFF + ((ua >> 16) & 1);
    unsigned ub = __float_as_uint(b); ub += 0x7FFF + ((ub >> 16) & 1);
    return (ua >> 16) | (ub & 0xFFFF0000u);
}
__device__ __forceinline__ float bf16lo(unsigned u) { return __uint_as_float(u << 16); }
__device__ __forceinline__ float bf16hi(unsigned u) { return __uint_as_float(u & 0xFFFF0000u); }
__device__ __forceinline__ unsigned rbf(float a) {                 // bf16 bits, RNE
    unsigned u = __float_as_uint(a);
    u += 0x7FFF + ((u >> 16) & 1);
    return u >> 16;
}
// split 8 f32 -> hi/lo bf16x8 (x = hi + lo to ~2^-17 rel)
__device__ __forceinline__ void split8(const float* xf, short8& hi, short8& lo) {
    S8U4 H, L;
#pragma unroll
    for (int i = 0; i < 4; ++i) {
        float a = xf[2 * i], b = xf[2 * i + 1];
        unsigned ha = rbf(a), hb = rbf(b);
        float ra = a - __uint_as_float(ha << 16);
        float rb = b - __uint_as_float(hb << 16);
        H.u[i] = ha | (hb << 16);
        L.u[i] = rbf(ra) | (rbf(rb) << 16);
    }
    hi = H.s; lo = L.s;
}

// ---------------- edge index loader (handles int32 or int64 storage) -------
__device__ __forceinline__ int edge_at(const int* __restrict__ ei, long long idx, int is64) {
    return is64 ? ei[idx << 1] : ei[idx];
}

// detect int64 vs int32 storage AND zero bkt_cnt (replaces hipMemsetAsync —
// round-15 finding: the runtime fill dispatch showed ~60us in-graph).
__global__ void k_detect(const int* __restrict__ ei, int* __restrict__ flag,
                         int* __restrict__ bkt_cnt, int nbkt) {
    __shared__ int nz;
    if (threadIdx.x == 0) nz = 0;
    __syncthreads();
    if (ei[2 * threadIdx.x + 1] != 0) atomicOr(&nz, 1);
    for (int i = threadIdx.x; i < nbkt; i += 256) bkt_cnt[i] = 0;
    __syncthreads();
    if (threadIdx.x == 0) *flag = (nz == 0) ? 1 : 0;
}

// ---------------- bucket binning (256 blocks x 1024 thr) -------------------
__global__ __launch_bounds__(1024) void k_bin_count(const int* __restrict__ ei, long long E,
                                                    const int* __restrict__ flag,
                                                    int* __restrict__ bkt_cnt, int nbkt) {
    __shared__ int hist[MAXBKT];
    int is64 = *flag;
    for (int i = threadIdx.x; i < nbkt; i += 1024) hist[i] = 0;
    __syncthreads();
    long long chunk = (E + gridDim.x - 1) / gridDim.x;
    long long lo = (long long)blockIdx.x * chunk;
    long long hi = lo + chunk; if (hi > E) hi = E;
    for (long long i = lo + threadIdx.x; i < hi; i += 1024)
        atomicAdd(&hist[edge_at(ei, E + i, is64) >> 8], 1);
    __syncthreads();
    for (int b = threadIdx.x; b < nbkt; b += 1024)
        if (hist[b]) atomicAdd(&bkt_cnt[b], hist[b]);
}

__global__ __launch_bounds__(512) void k_bscan(const int* __restrict__ bkt_cnt,
                                               int* __restrict__ bkt_base,
                                               int* __restrict__ bkt_cur, int nbkt) {
    __shared__ int sm[512];
    int t = threadIdx.x;
    int e0 = (2 * t < nbkt) ? bkt_cnt[2 * t] : 0;
    int e1 = (2 * t + 1 < nbkt) ? bkt_cnt[2 * t + 1] : 0;
    int pv = e0 + e1;
    sm[t] = pv;
    __syncthreads();
    for (int o = 1; o < 512; o <<= 1) {
        int x = (t >= o) ? sm[t - o] : 0;
        __syncthreads();
        sm[t] += x;
        __syncthreads();
    }
    int base = sm[t] - pv;
    if (2 * t < nbkt)     { bkt_base[2 * t] = base;          bkt_cur[2 * t] = base; }
    if (2 * t + 1 < nbkt) { bkt_base[2 * t + 1] = base + e0; bkt_cur[2 * t + 1] = base + e0; }
}

__global__ __launch_bounds__(1024) void k_bin_scatter(const int* __restrict__ ei, long long E,
                                                      const int* __restrict__ flag,
                                                      int* __restrict__ bkt_cur,
                                                      unsigned* __restrict__ packed, int nbkt) {
    __shared__ int hist[MAXBKT];
    int is64 = *flag;
    for (int i = threadIdx.x; i < nbkt; i += 1024) hist[i] = 0;
    __syncthreads();
    long long chunk = (E + gridDim.x - 1) / gridDim.x;
    long long lo = (long long)blockIdx.x * chunk;
    long long hi = lo + chunk; if (hi > E) hi = E;
    for (long long i = lo + threadIdx.x; i < hi; i += 1024)
        atomicAdd(&hist[edge_at(ei, E + i, is64) >> 8], 1);
    __syncthreads();
    for (int b = threadIdx.x; b < nbkt; b += 1024) {
        int c = hist[b];
        hist[b] = c ? atomicAdd(&bkt_cur[b], c) : 0;
    }
    __syncthreads();
    for (long long i = lo + threadIdx.x; i < hi; i += 1024) {
        int s = edge_at(ei, i, is64);
        int d = edge_at(ei, E + i, is64);
        int slot = atomicAdd(&hist[d >> 8], 1);
        packed[slot] = (unsigned)s | ((unsigned)(d & (NPB - 1)) << 20);
    }
}

// ---------------- per-bucket counting sort -> node-level CSR ---------------
__global__ __launch_bounds__(256) void k_bucket_csr(const unsigned* __restrict__ packed,
                                                    const int* __restrict__ bkt_base,
                                                    const int* __restrict__ bkt_cnt,
                                                    int* __restrict__ csr_src,
                                                    int* __restrict__ ptr,
                                                    int* __restrict__ cnt,
                                                    float* __restrict__ dinv, int n) {
    __shared__ int hist[NPB];
    __shared__ int off[NPB];
    hist[threadIdx.x] = 0;
    __syncthreads();
    int base = bkt_base[blockIdx.x], m = bkt_cnt[blockIdx.x];
    for (int i = threadIdx.x; i < m; i += 256)
        atomicAdd(&hist[packed[base + i] >> 20], 1);
    __syncthreads();
    off[threadIdx.x] = hist[threadIdx.x];
    __syncthreads();
    for (int o = 1; o < NPB; o <<= 1) {
        int v = (threadIdx.x >= o) ? off[threadIdx.x - o] : 0;
        __syncthreads();
        off[threadIdx.x] += v;
        __syncthreads();
    }
    int node = blockIdx.x * NPB + threadIdx.x;
    {
        int exc = off[threadIdx.x] - hist[threadIdx.x];
        if (node < n) {
            ptr[node]  = base + exc;
            cnt[node]  = hist[threadIdx.x];
            dinv[node] = rsqrtf((float)hist[threadIdx.x] + 1.0f);
        }
        hist[threadIdx.x] = exc;
    }
    __syncthreads();
    for (int i = threadIdx.x; i < m; i += 256) {
        unsigned w = packed[base + i];
        int r = atomicAdd(&hist[w >> 20], 1);
        csr_src[base + r] = (int)(w & 0xFFFFF);
    }
}

// ---------------- W1 fragment pre-build for MFMA ---------------------------
__global__ void k_wfrag(const float* __restrict__ W1, unsigned short* __restrict__ wf) {
    int idx = blockIdx.x * 256 + threadIdx.x;
    if (idx >= 8 * 2 * 2 * 64) return;
    int lane = idx & 63;
    int part = (idx >> 6) & 1;
    int tile = (idx >> 7) & 1;
    int s    = idx >> 8;
    int col = tile * 16 + (lane & 15);
    int k0  = s * 32 + (lane >> 4) * 8;
#pragma unroll
    for (int j = 0; j < 8; ++j) {
        float v = W1[(long long)(k0 + j) * HIDC + col];
        unsigned h = rbf(v);
        float r = v - __uint_as_float(h << 16);
        wf[(long long)idx * 8 + j] = (unsigned short)(part == 0 ? h : rbf(r));
    }
}

// ---------------- gemm1 via MFMA: h1b = bf16((x @ W1) * dinv) --------------
__global__ __launch_bounds__(256) void k_gemm1(const float* __restrict__ x,
                                               const unsigned short* __restrict__ wf,
                                               const float* __restrict__ dinv,
                                               unsigned short* __restrict__ h1b_us, int n) {
    const int t = threadIdx.x;
    const int l = t & 63;
    const int w = t >> 6;
    const long long nb0 = (long long)blockIdx.x * 64 + w * 16;   // wave's 16 nodes
    const int arow = l & 15;
    const int kg = l >> 4;                 // k-chunk 0..3
    const long long nodeA = nb0 + arow;
    const bool loadA = nodeA < n;
    f32x4 acc0 = {0.f, 0.f, 0.f, 0.f}, acc1 = {0.f, 0.f, 0.f, 0.f};

#pragma unroll
    for (int s = 0; s < 8; ++s) {
        float xf[8];
        if (loadA) {
            float4 v0 = *(const float4*)(x + nodeA * IN_C + s * 32 + kg * 8);
            float4 v1 = *(const float4*)(x + nodeA * IN_C + s * 32 + kg * 8 + 4);
            xf[0] = v0.x; xf[1] = v0.y; xf[2] = v0.z; xf[3] = v0.w;
            xf[4] = v1.x; xf[5] = v1.y; xf[6] = v1.z; xf[7] = v1.w;
        } else {
#pragma unroll
            for (int j = 0; j < 8; ++j) xf[j] = 0.f;
        }
        short8 ah, al;
        split8(xf, ah, al);
        const unsigned short* base = wf + ((long long)(s * 4) * 64 + l) * 8;
        short8 bh0 = *(const short8*)(base);
        short8 bl0 = *(const short8*)(base + 64 * 8);
        short8 bh1 = *(const short8*)(base + 2 * 64 * 8);
        short8 bl1 = *(const short8*)(base + 3 * 64 * 8);
        acc0 = __builtin_amdgcn_mfma_f32_16x16x32_bf16(ah, bh0, acc0, 0, 0, 0);
        acc0 = __builtin_amdgcn_mfma_f32_16x16x32_bf16(ah, bl0, acc0, 0, 0, 0);
        acc0 = __builtin_amdgcn_mfma_f32_16x16x32_bf16(al, bh0, acc0, 0, 0, 0);
        acc1 = __builtin_amdgcn_mfma_f32_16x16x32_bf16(ah, bh1, acc1, 0, 0, 0);
        acc1 = __builtin_amdgcn_mfma_f32_16x16x32_bf16(ah, bl1, acc1, 0, 0, 0);
        acc1 = __builtin_amdgcn_mfma_f32_16x16x32_bf16(al, bh1, acc1, 0, 0, 0);
    }
    // D layout (m89-verified): row = (l>>4)*4 + r, col = l&15
#pragma unroll
    for (int r = 0; r < 4; ++r) {
        long long nd = nb0 + (l >> 4) * 4 + r;
        if (nd < n) {
            float di = dinv[nd];
            h1b_us[nd * 32 + (l & 15)]      = (unsigned short)rbf(acc0[r] * di);
            h1b_us[nd * 32 + 16 + (l & 15)] = (unsigned short)rbf(acc1[r] * di);
        }
    }
}

// ---------------- layer-1 pull aggregation (bf16 gathers) ------------------
__global__ __launch_bounds__(256) void k_agg1csr(const int* __restrict__ ptr,
                                                 const int* __restrict__ cnt,
                                                 const int* __restrict__ csr_src,
                                                 const float* __restrict__ dinv,
                                                 const unsigned* __restrict__ h1b,
                                                 const float* __restrict__ b1,
                                                 float* __restrict__ h1r, int n) {
    long long g = (long long)blockIdx.x * blockDim.x + threadIdx.x;
    int node = (int)(g >> 4);
    int cp = (int)(g & 15);
    if (node >= n) return;
    unsigned us = h1b[(long long)node * 16 + cp];
    float accL = bf16lo(us), accH = bf16hi(us);
    int st = ptr[node], deg = cnt[node];
    int j = 0;
    for (; j + 3 < deg; j += 4) {
        int s0 = csr_src[st + j], s1 = csr_src[st + j + 1];
        int s2 = csr_src[st + j + 2], s3 = csr_src[st + j + 3];
        unsigned u0 = h1b[(long long)s0 * 16 + cp];
        unsigned u1 = h1b[(long long)s1 * 16 + cp];
        unsigned u2 = h1b[(long long)s2 * 16 + cp];
        unsigned u3 = h1b[(long long)s3 * 16 + cp];
        accL += (bf16lo(u0) + bf16lo(u1)) + (bf16lo(u2) + bf16lo(u3));
        accH += (bf16hi(u0) + bf16hi(u1)) + (bf16hi(u2) + bf16hi(u3));
    }
    for (; j < deg; ++j) {
        unsigned u = h1b[(long long)csr_src[st + j] * 16 + cp];
        accL += bf16lo(u); accH += bf16hi(u);
    }
    float di = dinv[node];
    float vL = accL * di + b1[2 * cp];
    float vH = accH * di + b1[2 * cp + 1];
    *(float2*)(h1r + (long long)node * HIDC + 2 * cp) =
        make_float2(vL > 0.f ? vL : 0.f, vH > 0.f ? vH : 0.f);
}

// ---------------- gemm2: h2b = bf16((h1r @ W2) * dinv) ---------------------
__global__ __launch_bounds__(256) void k_gemm2(const float* __restrict__ h1,
                                               const float* __restrict__ W2,
                                               const float* __restrict__ dinv,
                                               unsigned* __restrict__ h2b, int n) {
    const int t = threadIdx.x;
    const int oq = (t & 3) * 4;
    const long long node = (long long)blockIdx.x * 64 + (t >> 2);
    if (node >= n) return;
    const float* __restrict__ xp = h1 + node * HIDC;
    float a0 = 0.f, a1 = 0.f, a2 = 0.f, a3 = 0.f;
#pragma unroll
    for (int k0 = 0; k0 < HIDC; k0 += 8) {
        float4 xv0 = *(const float4*)(xp + k0);
        float4 xv1 = *(const float4*)(xp + k0 + 4);
        const float* __restrict__ wp = W2 + (long long)k0 * OUTC + oq;
        float4 w0 = *(const float4*)(wp + 0 * OUTC);
        float4 w1 = *(const float4*)(wp + 1 * OUTC);
        float4 w2 = *(const float4*)(wp + 2 * OUTC);
        float4 w3 = *(const float4*)(wp + 3 * OUTC);
        float4 w4 = *(const float4*)(wp + 4 * OUTC);
        float4 w5 = *(const float4*)(wp + 5 * OUTC);
        float4 w6 = *(const float4*)(wp + 6 * OUTC);
        float4 w7 = *(const float4*)(wp + 7 * OUTC);
        a0 = fmaf(xv0.x, w0.x, a0); a1 = fmaf(xv0.x, w0.y, a1);
        a2 = fmaf(xv0.x, w0.z, a2); a3 = fmaf(xv0.x, w0.w, a3);
        a0 = fmaf(xv0.y, w1.x, a0); a1 = fmaf(xv0.y, w1.y, a1);
        a2 = fmaf(xv0.y, w1.z, a2); a3 = fmaf(xv0.y, w1.w, a3);
        a0 = fmaf(xv0.z, w2.x, a0); a1 = fmaf(xv0.z, w2.y, a1);
        a2 = fmaf(xv0.z, w2.z, a2); a3 = fmaf(xv0.z, w2.w, a3);
        a0 = fmaf(xv0.w, w3.x, a0); a1 = fmaf(xv0.w, w3.y, a1);
        a2 = fmaf(xv0.w, w3.z, a2); a3 = fmaf(xv0.w, w3.w, a3);
        a0 = fmaf(xv1.x, w4.x, a0); a1 = fmaf(xv1.x, w4.y, a1);
        a2 = fmaf(xv1.x, w4.z, a2); a3 = fmaf(xv1.x, w4.w, a3);
        a0 = fmaf(xv1.y, w5.x, a0); a1 = fmaf(xv1.y, w5.y, a1);
        a2 = fmaf(xv1.y, w5.z, a2); a3 = fmaf(xv1.y, w5.w, a3);
        a0 = fmaf(xv1.z, w6.x, a0); a1 = fmaf(xv1.z, w6.y, a1);
        a2 = fmaf(xv1.z, w6.z, a2); a3 = fmaf(xv1.z, w6.w, a3);
        a0 = fmaf(xv1.w, w7.x, a0); a1 = fmaf(xv1.w, w7.y, a1);
        a2 = fmaf(xv1.w, w7.z, a2); a3 = fmaf(xv1.w, w7.w, a3);
    }
    float di = dinv[node];
    uint2 p;
    p.x = bf16pair(a0 * di, a1 * di);
    p.y = bf16pair(a2 * di, a3 * di);
    *(uint2*)(h2b + node * (OUTC / 2) + oq / 2) = p;
}

// ---------------- layer-2 pull aggregation (bf16 gathers) -> d_out ---------
__global__ __launch_bounds__(256) void k_agg2csr(const int* __restrict__ ptr,
                                                 const int* __restrict__ cnt,
                                                 const int* __restrict__ csr_src,
                                                 const float* __restrict__ dinv,
                                                 const unsigned* __restrict__ h2b,
                                                 const float* __restrict__ b2,
                                                 float* __restrict__ out, int n) {
    long long g = (long long)blockIdx.x * blockDim.x + threadIdx.x;
    int node = (int)(g >> 3);
    int cp = (int)(g & 7);
    if (node >= n) return;
    unsigned us = h2b[(long long)node * 8 + cp];
    float accL = bf16lo(us), accH = bf16hi(us);
    int st = ptr[node], deg = cnt[node];
    int j = 0;
    for (; j + 3 < deg; j += 4) {
        int s0 = csr_src[st + j], s1 = csr_src[st + j + 1];
        int s2 = csr_src[st + j + 2], s3 = csr_src[st + j + 3];
        unsigned u0 = h2b[(long long)s0 * 8 + cp];
        unsigned u1 = h2b[(long long)s1 * 8 + cp];
        unsigned u2 = h2b[(long long)s2 * 8 + cp];
        unsigned u3 = h2b[(long long)s3 * 8 + cp];
        accL += (bf16lo(u0) + bf16lo(u1)) + (bf16lo(u2) + bf16lo(u3));
        accH += (bf16hi(u0) + bf16hi(u1)) + (bf16hi(u2) + bf16hi(u3));
    }
    for (; j < deg; ++j) {
        unsigned u = h2b[(long long)csr_src[st + j] * 8 + cp];
        accL += bf16lo(u); accH += bf16hi(u);
    }
    float di = dinv[node];
    *(float2*)(out + (long long)node * OUTC + 2 * cp) =
        make_float2(accL * di + b2[2 * cp], accH * di + b2[2 * cp + 1]);
}

extern "C" void kernel_launch(void* const* d_in, const int* in_sizes, int n_in,
                              void* d_out, int out_size, void* d_ws, size_t ws_size,
                              hipStream_t stream) {
    const float* x  = (const float*)d_in[0];
    const int*   ei = (const int*)d_in[1];
    const float* W1 = (const float*)d_in[2];
    const float* b1 = (const float*)d_in[3];
    const float* W2 = (const float*)d_in[4];
    const float* b2 = (const float*)d_in[5];
    const int n = in_sizes[0] / IN_C;            // 100000
    const long long E = in_sizes[1] / 2;         // 3200000
    float* out = (float*)d_out;

    const int nbkt = (n + NPB - 1) / NPB;        // 391

    char* ws = (char*)d_ws;
    size_t off = 0;
    auto alloc = [&](size_t bytes) { void* p = ws + off; off += (bytes + 255) & ~(size_t)255; return p; };
    int*      flag     = (int*)alloc(256);
    int*      bkt_cnt  = (int*)alloc((size_t)MAXBKT * 4);
    int*      bkt_base = (int*)alloc((size_t)MAXBKT * 4);
    int*      bkt_cur  = (int*)alloc((size_t)MAXBKT * 4);
    float*    dinv     = (float*)alloc((size_t)n * 4);
    int*      cnt      = (int*)alloc((size_t)n * 4);
    int*      ptr      = (int*)alloc((size_t)n * 4);
    unsigned* packed   = (unsigned*)alloc((size_t)E * 4);
    int*      csr_src  = (int*)alloc((size_t)E * 4);
    unsigned short* wf = (unsigned short*)alloc(8 * 2 * 2 * 64 * 8 * 2);  // 32 KB
    unsigned* h1b      = (unsigned*)alloc((size_t)n * (HIDC / 2) * 4);    // bf16 [n][32]
    float*    h1r      = (float*)alloc((size_t)n * HIDC * 4);
    unsigned* h2b      = (unsigned*)alloc((size_t)n * (OUTC / 2) * 4);    // bf16 [n][16]

    k_detect<<<1, 256, 0, stream>>>(ei, flag, bkt_cnt, nbkt);
    k_wfrag<<<8, 256, 0, stream>>>(W1, wf);
    k_bin_count<<<256, 1024, 0, stream>>>(ei, E, flag, bkt_cnt, nbkt);
    k_bscan<<<1, 512, 0, stream>>>(bkt_cnt, bkt_base, bkt_cur, nbkt);
    k_bin_scatter<<<256, 1024, 0, stream>>>(ei, E, flag, bkt_cur, packed, nbkt);
    k_bucket_csr<<<nbkt, NPB, 0, stream>>>(packed, bkt_base, bkt_cnt, csr_src, ptr, cnt, dinv, n);

    k_gemm1<<<(n + 63) / 64, 256, 0, stream>>>(x, wf, dinv, (unsigned short*)h1b, n);
    k_agg1csr<<<(int)(((long long)n * 16 + 255) / 256), 256, 0, stream>>>(
        ptr, cnt, csr_src, dinv, h1b, b1, h1r, n);
    k_gemm2<<<(n + 63) / 64, 256, 0, stream>>>(h1r, W2, dinv, h2b, n);
    k_agg2csr<<<(int)(((long long)n * 8 + 255) / 256), 256, 0, stream>>>(
        ptr, cnt, csr_src, dinv, h2b, b2, out, n);
}

// Round 17
// 177.002 us; speedup vs baseline: 1.4622x; 1.0283x over previous
//
#include <hip/hip_runtime.h>

#define IN_C 256
#define HIDC 32
#define OUTC 16
#define NPB  256          // nodes per bucket (d_local = 8 bits)
#define MAXBKT 800
#define CAP  16384        // per-bucket packed capacity (uniform mean 8184 -> 90 sigma safe)
#define EPB  12288        // edges per scatter block (LDS cache)

typedef __attribute__((ext_vector_type(8))) short short8;
typedef __attribute__((ext_vector_type(4))) float f32x4;
union S8U4 { short8 s; unsigned u[4]; };

// ---------------- bf16 helpers ---------------------------------------------
__device__ __forceinline__ unsigned bf16pair(float a, float b) {   // RNE pack
    unsigned ua = __float_as_uint(a); ua += 0x7FFF + ((ua >> 16) & 1);
    unsigned ub = __float_as_uint(b); ub += 0x7FFF + ((ub >> 16) & 1);
    return (ua >> 16) | (ub & 0xFFFF0000u);
}
__device__ __forceinline__ float bf16lo(unsigned u) { return __uint_as_float(u << 16); }
__device__ __forceinline__ float bf16hi(unsigned u) { return __uint_as_float(u & 0xFFFF0000u); }
__device__ __forceinline__ unsigned rbf(float a) {                 // bf16 bits, RNE
    unsigned u = __float_as_uint(a);
    u += 0x7FFF + ((u >> 16) & 1);
    return u >> 16;
}
// split 8 f32 -> hi/lo bf16x8 (x = hi + lo to ~2^-17 rel)
__device__ __forceinline__ void split8(const float* xf, short8& hi, short8& lo) {
    S8U4 H, L;
#pragma unroll
    for (int i = 0; i < 4; ++i) {
        float a = xf[2 * i], b = xf[2 * i + 1];
        unsigned ha = rbf(a), hb = rbf(b);
        float ra = a - __uint_as_float(ha << 16);
        float rb = b - __uint_as_float(hb << 16);
        H.u[i] = ha | (hb << 16);
        L.u[i] = rbf(ra) | (rbf(rb) << 16);
    }
    hi = H.s; lo = L.s;
}

// ---------------- edge index loader (handles int32 or int64 storage) -------
__device__ __forceinline__ int edge_at(const int* __restrict__ ei, long long idx, int is64) {
    return is64 ? ei[idx << 1] : ei[idx];
}

// detect int64 vs int32 storage AND init bkt_cur[b] = b*CAP (fixed-capacity
// buckets — round-17: k_bin_count + k_bscan eliminated).
__global__ void k_detect(const int* __restrict__ ei, int* __restrict__ flag,
                         int* __restrict__ bkt_cur, int nbkt) {
    __shared__ int nz;
    if (threadIdx.x == 0) nz = 0;
    __syncthreads();
    if (ei[2 * threadIdx.x + 1] != 0) atomicOr(&nz, 1);
    for (int i = threadIdx.x; i < nbkt; i += 256) bkt_cur[i] = i * CAP;
    __syncthreads();
    if (threadIdx.x == 0) *flag = (nz == 0) ? 1 : 0;
}

// ---------------- single-pass bucket scatter --------------------------------
// Reads src+dst ONCE (51 MB total vs round-16's 128 MB across count+scatter),
// caches packed word + bucket id in LDS, reserves per-(block,bucket) runs
// from fixed-capacity cursors, scatters from LDS. 1024 thr, ~77 KB LDS.
__global__ __launch_bounds__(1024) void k_bin_scatter(const int* __restrict__ ei, long long E,
                                                      const int* __restrict__ flag,
                                                      int* __restrict__ bkt_cur,
                                                      unsigned* __restrict__ packed, int nbkt) {
    __shared__ unsigned ecw[EPB];          // 48 KB packed words
    __shared__ unsigned short ecb[EPB];    // 24 KB bucket ids
    __shared__ int hist[MAXBKT];           // 3.2 KB
    int is64 = *flag;
    for (int i = threadIdx.x; i < nbkt; i += 1024) hist[i] = 0;
    __syncthreads();
    long long lo = (long long)blockIdx.x * EPB;
    int m = (int)((E - lo) < EPB ? (E - lo) : EPB);
    for (int i = threadIdx.x; i < m; i += 1024) {
        int s = edge_at(ei, lo + i, is64);
        int d = edge_at(ei, E + lo + i, is64);
        ecw[i] = (unsigned)s | ((unsigned)(d & (NPB - 1)) << 20);
        ecb[i] = (unsigned short)(d >> 8);
        atomicAdd(&hist[d >> 8], 1);
    }
    __syncthreads();
    for (int b = threadIdx.x; b < nbkt; b += 1024) {
        int c = hist[b];
        hist[b] = c ? atomicAdd(&bkt_cur[b], c) : 0;   // hist now = run cursor
    }
    __syncthreads();
    for (int i = threadIdx.x; i < m; i += 1024) {
        int slot = atomicAdd(&hist[ecb[i]], 1);
        packed[slot] = ecw[i];
    }
}

// ---------------- per-bucket counting sort -> node-level CSR ---------------
__global__ __launch_bounds__(256) void k_bucket_csr(const unsigned* __restrict__ packed,
                                                    const int* __restrict__ bkt_cur,
                                                    int* __restrict__ csr_src,
                                                    int* __restrict__ ptr,
                                                    int* __restrict__ cnt,
                                                    float* __restrict__ dinv, int n) {
    __shared__ int hist[NPB];
    __shared__ int off[NPB];
    hist[threadIdx.x] = 0;
    __syncthreads();
    int base = blockIdx.x * CAP;
    int m = bkt_cur[blockIdx.x] - base;
    for (int i = threadIdx.x; i < m; i += 256)
        atomicAdd(&hist[packed[base + i] >> 20], 1);
    __syncthreads();
    off[threadIdx.x] = hist[threadIdx.x];
    __syncthreads();
    for (int o = 1; o < NPB; o <<= 1) {
        int v = (threadIdx.x >= o) ? off[threadIdx.x - o] : 0;
        __syncthreads();
        off[threadIdx.x] += v;
        __syncthreads();
    }
    int node = blockIdx.x * NPB + threadIdx.x;
    {
        int exc = off[threadIdx.x] - hist[threadIdx.x];
        if (node < n) {
            ptr[node]  = base + exc;
            cnt[node]  = hist[threadIdx.x];
            dinv[node] = rsqrtf((float)hist[threadIdx.x] + 1.0f);
        }
        hist[threadIdx.x] = exc;
    }
    __syncthreads();
    for (int i = threadIdx.x; i < m; i += 256) {
        unsigned w = packed[base + i];
        int r = atomicAdd(&hist[w >> 20], 1);
        csr_src[base + r] = (int)(w & 0xFFFFF);
    }
}

// ---------------- W1 fragment pre-build for MFMA ---------------------------
__global__ void k_wfrag(const float* __restrict__ W1, unsigned short* __restrict__ wf) {
    int idx = blockIdx.x * 256 + threadIdx.x;
    if (idx >= 8 * 2 * 2 * 64) return;
    int lane = idx & 63;
    int part = (idx >> 6) & 1;
    int tile = (idx >> 7) & 1;
    int s    = idx >> 8;
    int col = tile * 16 + (lane & 15);
    int k0  = s * 32 + (lane >> 4) * 8;
#pragma unroll
    for (int j = 0; j < 8; ++j) {
        float v = W1[(long long)(k0 + j) * HIDC + col];
        unsigned h = rbf(v);
        float r = v - __uint_as_float(h << 16);
        wf[(long long)idx * 8 + j] = (unsigned short)(part == 0 ? h : rbf(r));
    }
}

// ---------------- gemm1 via MFMA: h1b = bf16((x @ W1) * dinv) --------------
__global__ __launch_bounds__(256) void k_gemm1(const float* __restrict__ x,
                                               const unsigned short* __restrict__ wf,
                                               const float* __restrict__ dinv,
                                               unsigned short* __restrict__ h1b_us, int n) {
    const int t = threadIdx.x;
    const int l = t & 63;
    const int w = t >> 6;
    const long long nb0 = (long long)blockIdx.x * 64 + w * 16;   // wave's 16 nodes
    const int arow = l & 15;
    const int kg = l >> 4;                 // k-chunk 0..3
    const long long nodeA = nb0 + arow;
    const bool loadA = nodeA < n;
    f32x4 acc0 = {0.f, 0.f, 0.f, 0.f}, acc1 = {0.f, 0.f, 0.f, 0.f};

#pragma unroll
    for (int s = 0; s < 8; ++s) {
        float xf[8];
        if (loadA) {
            float4 v0 = *(const float4*)(x + nodeA * IN_C + s * 32 + kg * 8);
            float4 v1 = *(const float4*)(x + nodeA * IN_C + s * 32 + kg * 8 + 4);
            xf[0] = v0.x; xf[1] = v0.y; xf[2] = v0.z; xf[3] = v0.w;
            xf[4] = v1.x; xf[5] = v1.y; xf[6] = v1.z; xf[7] = v1.w;
        } else {
#pragma unroll
            for (int j = 0; j < 8; ++j) xf[j] = 0.f;
        }
        short8 ah, al;
        split8(xf, ah, al);
        const unsigned short* base = wf + ((long long)(s * 4) * 64 + l) * 8;
        short8 bh0 = *(const short8*)(base);
        short8 bl0 = *(const short8*)(base + 64 * 8);
        short8 bh1 = *(const short8*)(base + 2 * 64 * 8);
        short8 bl1 = *(const short8*)(base + 3 * 64 * 8);
        acc0 = __builtin_amdgcn_mfma_f32_16x16x32_bf16(ah, bh0, acc0, 0, 0, 0);
        acc0 = __builtin_amdgcn_mfma_f32_16x16x32_bf16(ah, bl0, acc0, 0, 0, 0);
        acc0 = __builtin_amdgcn_mfma_f32_16x16x32_bf16(al, bh0, acc0, 0, 0, 0);
        acc1 = __builtin_amdgcn_mfma_f32_16x16x32_bf16(ah, bh1, acc1, 0, 0, 0);
        acc1 = __builtin_amdgcn_mfma_f32_16x16x32_bf16(ah, bl1, acc1, 0, 0, 0);
        acc1 = __builtin_amdgcn_mfma_f32_16x16x32_bf16(al, bh1, acc1, 0, 0, 0);
    }
    // D layout (m89-verified): row = (l>>4)*4 + r, col = l&15
#pragma unroll
    for (int r = 0; r < 4; ++r) {
        long long nd = nb0 + (l >> 4) * 4 + r;
        if (nd < n) {
            float di = dinv[nd];
            h1b_us[nd * 32 + (l & 15)]      = (unsigned short)rbf(acc0[r] * di);
            h1b_us[nd * 32 + 16 + (l & 15)] = (unsigned short)rbf(acc1[r] * di);
        }
    }
}

// ---------------- layer-1 pull aggregation (bf16 gathers) ------------------
__global__ __launch_bounds__(256) void k_agg1csr(const int* __restrict__ ptr,
                                                 const int* __restrict__ cnt,
                                                 const int* __restrict__ csr_src,
                                                 const float* __restrict__ dinv,
                                                 const unsigned* __restrict__ h1b,
                                                 const float* __restrict__ b1,
                                                 float* __restrict__ h1r, int n) {
    long long g = (long long)blockIdx.x * blockDim.x + threadIdx.x;
    int node = (int)(g >> 4);
    int cp = (int)(g & 15);
    if (node >= n) return;
    unsigned us = h1b[(long long)node * 16 + cp];
    float accL = bf16lo(us), accH = bf16hi(us);
    int st = ptr[node], deg = cnt[node];
    int j = 0;
    for (; j + 3 < deg; j += 4) {
        int s0 = csr_src[st + j], s1 = csr_src[st + j + 1];
        int s2 = csr_src[st + j + 2], s3 = csr_src[st + j + 3];
        unsigned u0 = h1b[(long long)s0 * 16 + cp];
        unsigned u1 = h1b[(long long)s1 * 16 + cp];
        unsigned u2 = h1b[(long long)s2 * 16 + cp];
        unsigned u3 = h1b[(long long)s3 * 16 + cp];
        accL += (bf16lo(u0) + bf16lo(u1)) + (bf16lo(u2) + bf16lo(u3));
        accH += (bf16hi(u0) + bf16hi(u1)) + (bf16hi(u2) + bf16hi(u3));
    }
    for (; j < deg; ++j) {
        unsigned u = h1b[(long long)csr_src[st + j] * 16 + cp];
        accL += bf16lo(u); accH += bf16hi(u);
    }
    float di = dinv[node];
    float vL = accL * di + b1[2 * cp];
    float vH = accH * di + b1[2 * cp + 1];
    *(float2*)(h1r + (long long)node * HIDC + 2 * cp) =
        make_float2(vL > 0.f ? vL : 0.f, vH > 0.f ? vH : 0.f);
}

// ---------------- gemm2: h2b = bf16((h1r @ W2) * dinv) ---------------------
__global__ __launch_bounds__(256) void k_gemm2(const float* __restrict__ h1,
                                               const float* __restrict__ W2,
                                               const float* __restrict__ dinv,
                                               unsigned* __restrict__ h2b, int n) {
    const int t = threadIdx.x;
    const int oq = (t & 3) * 4;
    const long long node = (long long)blockIdx.x * 64 + (t >> 2);
    if (node >= n) return;
    const float* __restrict__ xp = h1 + node * HIDC;
    float a0 = 0.f, a1 = 0.f, a2 = 0.f, a3 = 0.f;
#pragma unroll
    for (int k0 = 0; k0 < HIDC; k0 += 8) {
        float4 xv0 = *(const float4*)(xp + k0);
        float4 xv1 = *(const float4*)(xp + k0 + 4);
        const float* __restrict__ wp = W2 + (long long)k0 * OUTC + oq;
        float4 w0 = *(const float4*)(wp + 0 * OUTC);
        float4 w1 = *(const float4*)(wp + 1 * OUTC);
        float4 w2 = *(const float4*)(wp + 2 * OUTC);
        float4 w3 = *(const float4*)(wp + 3 * OUTC);
        float4 w4 = *(const float4*)(wp + 4 * OUTC);
        float4 w5 = *(const float4*)(wp + 5 * OUTC);
        float4 w6 = *(const float4*)(wp + 6 * OUTC);
        float4 w7 = *(const float4*)(wp + 7 * OUTC);
        a0 = fmaf(xv0.x, w0.x, a0); a1 = fmaf(xv0.x, w0.y, a1);
        a2 = fmaf(xv0.x, w0.z, a2); a3 = fmaf(xv0.x, w0.w, a3);
        a0 = fmaf(xv0.y, w1.x, a0); a1 = fmaf(xv0.y, w1.y, a1);
        a2 = fmaf(xv0.y, w1.z, a2); a3 = fmaf(xv0.y, w1.w, a3);
        a0 = fmaf(xv0.z, w2.x, a0); a1 = fmaf(xv0.z, w2.y, a1);
        a2 = fmaf(xv0.z, w2.z, a2); a3 = fmaf(xv0.z, w2.w, a3);
        a0 = fmaf(xv0.w, w3.x, a0); a1 = fmaf(xv0.w, w3.y, a1);
        a2 = fmaf(xv0.w, w3.z, a2); a3 = fmaf(xv0.w, w3.w, a3);
        a0 = fmaf(xv1.x, w4.x, a0); a1 = fmaf(xv1.x, w4.y, a1);
        a2 = fmaf(xv1.x, w4.z, a2); a3 = fmaf(xv1.x, w4.w, a3);
        a0 = fmaf(xv1.y, w5.x, a0); a1 = fmaf(xv1.y, w5.y, a1);
        a2 = fmaf(xv1.y, w5.z, a2); a3 = fmaf(xv1.y, w5.w, a3);
        a0 = fmaf(xv1.z, w6.x, a0); a1 = fmaf(xv1.z, w6.y, a1);
        a2 = fmaf(xv1.z, w6.z, a2); a3 = fmaf(xv1.z, w6.w, a3);
        a0 = fmaf(xv1.w, w7.x, a0); a1 = fmaf(xv1.w, w7.y, a1);
        a2 = fmaf(xv1.w, w7.z, a2); a3 = fmaf(xv1.w, w7.w, a3);
    }
    float di = dinv[node];
    uint2 p;
    p.x = bf16pair(a0 * di, a1 * di);
    p.y = bf16pair(a2 * di, a3 * di);
    *(uint2*)(h2b + node * (OUTC / 2) + oq / 2) = p;
}

// ---------------- layer-2 pull aggregation (bf16 gathers) -> d_out ---------
__global__ __launch_bounds__(256) void k_agg2csr(const int* __restrict__ ptr,
                                                 const int* __restrict__ cnt,
                                                 const int* __restrict__ csr_src,
                                                 const float* __restrict__ dinv,
                                                 const unsigned* __restrict__ h2b,
                                                 const float* __restrict__ b2,
                                                 float* __restrict__ out, int n) {
    long long g = (long long)blockIdx.x * blockDim.x + threadIdx.x;
    int node = (int)(g >> 3);
    int cp = (int)(g & 7);
    if (node >= n) return;
    unsigned us = h2b[(long long)node * 8 + cp];
    float accL = bf16lo(us), accH = bf16hi(us);
    int st = ptr[node], deg = cnt[node];
    int j = 0;
    for (; j + 3 < deg; j += 4) {
        int s0 = csr_src[st + j], s1 = csr_src[st + j + 1];
        int s2 = csr_src[st + j + 2], s3 = csr_src[st + j + 3];
        unsigned u0 = h2b[(long long)s0 * 8 + cp];
        unsigned u1 = h2b[(long long)s1 * 8 + cp];
        unsigned u2 = h2b[(long long)s2 * 8 + cp];
        unsigned u3 = h2b[(long long)s3 * 8 + cp];
        accL += (bf16lo(u0) + bf16lo(u1)) + (bf16lo(u2) + bf16lo(u3));
        accH += (bf16hi(u0) + bf16hi(u1)) + (bf16hi(u2) + bf16hi(u3));
    }
    for (; j < deg; ++j) {
        unsigned u = h2b[(long long)csr_src[st + j] * 8 + cp];
        accL += bf16lo(u); accH += bf16hi(u);
    }
    float di = dinv[node];
    *(float2*)(out + (long long)node * OUTC + 2 * cp) =
        make_float2(accL * di + b2[2 * cp], accH * di + b2[2 * cp + 1]);
}

extern "C" void kernel_launch(void* const* d_in, const int* in_sizes, int n_in,
                              void* d_out, int out_size, void* d_ws, size_t ws_size,
                              hipStream_t stream) {
    const float* x  = (const float*)d_in[0];
    const int*   ei = (const int*)d_in[1];
    const float* W1 = (const float*)d_in[2];
    const float* b1 = (const float*)d_in[3];
    const float* W2 = (const float*)d_in[4];
    const float* b2 = (const float*)d_in[5];
    const int n = in_sizes[0] / IN_C;            // 100000
    const long long E = in_sizes[1] / 2;         // 3200000
    float* out = (float*)d_out;

    const int nbkt = (n + NPB - 1) / NPB;        // 391

    char* ws = (char*)d_ws;
    size_t off = 0;
    auto alloc = [&](size_t bytes) { void* p = ws + off; off += (bytes + 255) & ~(size_t)255; return p; };
    int*      flag     = (int*)alloc(256);
    int*      bkt_cur  = (int*)alloc((size_t)MAXBKT * 4);
    float*    dinv     = (float*)alloc((size_t)n * 4);
    int*      cnt      = (int*)alloc((size_t)n * 4);
    int*      ptr      = (int*)alloc((size_t)n * 4);
    unsigned* packed   = (unsigned*)alloc((size_t)nbkt * CAP * 4);      // 25.6 MB
    int*      csr_src  = (int*)alloc((size_t)nbkt * CAP * 4);           // 25.6 MB
    unsigned short* wf = (unsigned short*)alloc(8 * 2 * 2 * 64 * 8 * 2);  // 32 KB
    unsigned* h1b      = (unsigned*)alloc((size_t)n * (HIDC / 2) * 4);    // bf16 [n][32]
    float*    h1r      = (float*)alloc((size_t)n * HIDC * 4);
    unsigned* h2b      = (unsigned*)alloc((size_t)n * (OUTC / 2) * 4);    // bf16 [n][16]

    k_detect<<<1, 256, 0, stream>>>(ei, flag, bkt_cur, nbkt);
    k_wfrag<<<8, 256, 0, stream>>>(W1, wf);
    k_bin_scatter<<<(int)((E + EPB - 1) / EPB), 1024, 0, stream>>>(ei, E, flag, bkt_cur, packed, nbkt);
    k_bucket_csr<<<nbkt, NPB, 0, stream>>>(packed, bkt_cur, csr_src, ptr, cnt, dinv, n);

    k_gemm1<<<(n + 63) / 64, 256, 0, stream>>>(x, wf, dinv, (unsigned short*)h1b, n);
    k_agg1csr<<<(int)(((long long)n * 16 + 255) / 256), 256, 0, stream>>>(
        ptr, cnt, csr_src, dinv, h1b, b1, h1r, n);
    k_gemm2<<<(n + 63) / 64, 256, 0, stream>>>(h1r, W2, dinv, h2b, n);
    k_agg2csr<<<(int)(((long long)n * 8 + 255) / 256), 256, 0, stream>>>(
        ptr, cnt, csr_src, dinv, h2b, b2, out, n);
}

// Round 18
// 171.678 us; speedup vs baseline: 1.5075x; 1.0310x over previous
//
#include <hip/hip_runtime.h>

#define IN_C 256
#define HIDC 32
#define OUTC 16
#define NPB  256          // nodes per bucket (d_local = 8 bits)
#define MAXBKT 800
#define CAP  16384        // per-bucket packed capacity (uniform mean 8184 -> 90 sigma safe)
#define EPB  12288        // edges per scatter block
#define EPT  12           // edges per thread (register cache)

typedef __attribute__((ext_vector_type(8))) short short8;
typedef __attribute__((ext_vector_type(4))) float f32x4;
union S8U4 { short8 s; unsigned u[4]; };

// ---------------- bf16 helpers ---------------------------------------------
__device__ __forceinline__ unsigned bf16pair(float a, float b) {   // RNE pack
    unsigned ua = __float_as_uint(a); ua += 0x7FFF + ((ua >> 16) & 1);
    unsigned ub = __float_as_uint(b); ub += 0x7FFF + ((ub >> 16) & 1);
    return (ua >> 16) | (ub & 0xFFFF0000u);
}
__device__ __forceinline__ float bf16lo(unsigned u) { return __uint_as_float(u << 16); }
__device__ __forceinline__ float bf16hi(unsigned u) { return __uint_as_float(u & 0xFFFF0000u); }
__device__ __forceinline__ unsigned rbf(float a) {                 // bf16 bits, RNE
    unsigned u = __float_as_uint(a);
    u += 0x7FFF + ((u >> 16) & 1);
    return u >> 16;
}
// split 8 f32 -> hi/lo bf16x8 (x = hi + lo to ~2^-17 rel)
__device__ __forceinline__ void split8(const float* xf, short8& hi, short8& lo) {
    S8U4 H, L;
#pragma unroll
    for (int i = 0; i < 4; ++i) {
        float a = xf[2 * i], b = xf[2 * i + 1];
        unsigned ha = rbf(a), hb = rbf(b);
        float ra = a - __uint_as_float(ha << 16);
        float rb = b - __uint_as_float(hb << 16);
        H.u[i] = ha | (hb << 16);
        L.u[i] = rbf(ra) | (rbf(rb) << 16);
    }
    hi = H.s; lo = L.s;
}

// ---------------- edge index loader (handles int32 or int64 storage) -------
__device__ __forceinline__ int edge_at(const int* __restrict__ ei, long long idx, int is64) {
    return is64 ? ei[idx << 1] : ei[idx];
}

// detect int64 vs int32 storage AND init bkt_cur[b] = b*CAP (fixed-capacity
// buckets — round-17: count/scan eliminated).
__global__ void k_detect(const int* __restrict__ ei, int* __restrict__ flag,
                         int* __restrict__ bkt_cur, int nbkt) {
    __shared__ int nz;
    if (threadIdx.x == 0) nz = 0;
    __syncthreads();
    if (ei[2 * threadIdx.x + 1] != 0) atomicOr(&nz, 1);
    for (int i = threadIdx.x; i < nbkt; i += 256) bkt_cur[i] = i * CAP;
    __syncthreads();
    if (threadIdx.x == 0) *flag = (nz == 0) ? 1 : 0;
}

// ---------------- single-pass bucket scatter (register edge cache) ---------
// Round-18: 12 edges/thread in REGISTERS (statically unrolled) instead of a
// 72KB LDS cache — removes 24K LDS ops/block and the LDS occupancy cap.
__global__ __launch_bounds__(1024) void k_bin_scatter(const int* __restrict__ ei, long long E,
                                                      const int* __restrict__ flag,
                                                      int* __restrict__ bkt_cur,
                                                      unsigned* __restrict__ packed, int nbkt) {
    __shared__ int hist[MAXBKT];           // 3.2 KB only
    int is64 = *flag;
    for (int i = threadIdx.x; i < nbkt; i += 1024) hist[i] = 0;
    __syncthreads();
    long long lo = (long long)blockIdx.x * EPB;
    int m = (int)((E - lo) < EPB ? (E - lo) : EPB);
    unsigned ew[EPT];
    int      eb[EPT];
#pragma unroll
    for (int j = 0; j < EPT; ++j) {
        int i = j * 1024 + (int)threadIdx.x;
        eb[j] = -1;
        if (i < m) {
            int s = edge_at(ei, lo + i, is64);
            int d = edge_at(ei, E + lo + i, is64);
            ew[j] = (unsigned)s | ((unsigned)(d & (NPB - 1)) << 20);
            eb[j] = d >> 8;
            atomicAdd(&hist[eb[j]], 1);
        }
    }
    __syncthreads();
    for (int b = threadIdx.x; b < nbkt; b += 1024) {
        int c = hist[b];
        hist[b] = c ? atomicAdd(&bkt_cur[b], c) : 0;   // hist now = run cursor
    }
    __syncthreads();
#pragma unroll
    for (int j = 0; j < EPT; ++j) {
        if (eb[j] >= 0) {
            int slot = atomicAdd(&hist[eb[j]], 1);
            packed[slot] = ew[j];
        }
    }
}

// ---------------- per-bucket counting sort -> node-level CSR ---------------
__global__ __launch_bounds__(256) void k_bucket_csr(const unsigned* __restrict__ packed,
                                                    const int* __restrict__ bkt_cur,
                                                    int* __restrict__ csr_src,
                                                    int* __restrict__ ptr,
                                                    int* __restrict__ cnt,
                                                    float* __restrict__ dinv, int n) {
    __shared__ int hist[NPB];
    __shared__ int off[NPB];
    hist[threadIdx.x] = 0;
    __syncthreads();
    int base = blockIdx.x * CAP;
    int m = bkt_cur[blockIdx.x] - base;
    for (int i = threadIdx.x; i < m; i += 256)
        atomicAdd(&hist[packed[base + i] >> 20], 1);
    __syncthreads();
    off[threadIdx.x] = hist[threadIdx.x];
    __syncthreads();
    for (int o = 1; o < NPB; o <<= 1) {
        int v = (threadIdx.x >= o) ? off[threadIdx.x - o] : 0;
        __syncthreads();
        off[threadIdx.x] += v;
        __syncthreads();
    }
    int node = blockIdx.x * NPB + threadIdx.x;
    {
        int exc = off[threadIdx.x] - hist[threadIdx.x];
        if (node < n) {
            ptr[node]  = base + exc;
            cnt[node]  = hist[threadIdx.x];
            dinv[node] = rsqrtf((float)hist[threadIdx.x] + 1.0f);
        }
        hist[threadIdx.x] = exc;
    }
    __syncthreads();
    for (int i = threadIdx.x; i < m; i += 256) {
        unsigned w = packed[base + i];
        int r = atomicAdd(&hist[w >> 20], 1);
        csr_src[base + r] = (int)(w & 0xFFFFF);
    }
}

// ---------------- W1 fragment pre-build for MFMA ---------------------------
__global__ void k_wfrag(const float* __restrict__ W1, unsigned short* __restrict__ wf) {
    int idx = blockIdx.x * 256 + threadIdx.x;
    if (idx >= 8 * 2 * 2 * 64) return;
    int lane = idx & 63;
    int part = (idx >> 6) & 1;
    int tile = (idx >> 7) & 1;
    int s    = idx >> 8;
    int col = tile * 16 + (lane & 15);
    int k0  = s * 32 + (lane >> 4) * 8;
#pragma unroll
    for (int j = 0; j < 8; ++j) {
        float v = W1[(long long)(k0 + j) * HIDC + col];
        unsigned h = rbf(v);
        float r = v - __uint_as_float(h << 16);
        wf[(long long)idx * 8 + j] = (unsigned short)(part == 0 ? h : rbf(r));
    }
}

// ---------------- gemm1 via MFMA: h1b = bf16((x @ W1) * dinv) --------------
__global__ __launch_bounds__(256) void k_gemm1(const float* __restrict__ x,
                                               const unsigned short* __restrict__ wf,
                                               const float* __restrict__ dinv,
                                               unsigned short* __restrict__ h1b_us, int n) {
    const int t = threadIdx.x;
    const int l = t & 63;
    const int w = t >> 6;
    const long long nb0 = (long long)blockIdx.x * 64 + w * 16;   // wave's 16 nodes
    const int arow = l & 15;
    const int kg = l >> 4;                 // k-chunk 0..3
    const long long nodeA = nb0 + arow;
    const bool loadA = nodeA < n;
    f32x4 acc0 = {0.f, 0.f, 0.f, 0.f}, acc1 = {0.f, 0.f, 0.f, 0.f};

#pragma unroll
    for (int s = 0; s < 8; ++s) {
        float xf[8];
        if (loadA) {
            float4 v0 = *(const float4*)(x + nodeA * IN_C + s * 32 + kg * 8);
            float4 v1 = *(const float4*)(x + nodeA * IN_C + s * 32 + kg * 8 + 4);
            xf[0] = v0.x; xf[1] = v0.y; xf[2] = v0.z; xf[3] = v0.w;
            xf[4] = v1.x; xf[5] = v1.y; xf[6] = v1.z; xf[7] = v1.w;
        } else {
#pragma unroll
            for (int j = 0; j < 8; ++j) xf[j] = 0.f;
        }
        short8 ah, al;
        split8(xf, ah, al);
        const unsigned short* base = wf + ((long long)(s * 4) * 64 + l) * 8;
        short8 bh0 = *(const short8*)(base);
        short8 bl0 = *(const short8*)(base + 64 * 8);
        short8 bh1 = *(const short8*)(base + 2 * 64 * 8);
        short8 bl1 = *(const short8*)(base + 3 * 64 * 8);
        acc0 = __builtin_amdgcn_mfma_f32_16x16x32_bf16(ah, bh0, acc0, 0, 0, 0);
        acc0 = __builtin_amdgcn_mfma_f32_16x16x32_bf16(ah, bl0, acc0, 0, 0, 0);
        acc0 = __builtin_amdgcn_mfma_f32_16x16x32_bf16(al, bh0, acc0, 0, 0, 0);
        acc1 = __builtin_amdgcn_mfma_f32_16x16x32_bf16(ah, bh1, acc1, 0, 0, 0);
        acc1 = __builtin_amdgcn_mfma_f32_16x16x32_bf16(ah, bl1, acc1, 0, 0, 0);
        acc1 = __builtin_amdgcn_mfma_f32_16x16x32_bf16(al, bh1, acc1, 0, 0, 0);
    }
    // D layout (m89-verified): row = (l>>4)*4 + r, col = l&15
#pragma unroll
    for (int r = 0; r < 4; ++r) {
        long long nd = nb0 + (l >> 4) * 4 + r;
        if (nd < n) {
            float di = dinv[nd];
            h1b_us[nd * 32 + (l & 15)]      = (unsigned short)rbf(acc0[r] * di);
            h1b_us[nd * 32 + 16 + (l & 15)] = (unsigned short)rbf(acc1[r] * di);
        }
    }
}

// ---------------- fused layer-1 aggregation + gemm2 ------------------------
// Phase A (all 256 thr): pull-aggregate bf16 h1b, relu -> hs[16][33] in LDS.
// Phase B (128 thr): h2 = (hs @ W2)*dinv, bf16-pack -> h2b. Eliminates the
// h1r global round-trip (25.6 MB) and the separate gemm2 dispatch.
__global__ __launch_bounds__(256) void k_agg1g2(const int* __restrict__ ptr,
                                                const int* __restrict__ cnt,
                                                const int* __restrict__ csr_src,
                                                const float* __restrict__ dinv,
                                                const unsigned* __restrict__ h1b,
                                                const float* __restrict__ b1,
                                                const float* __restrict__ W2,
                                                unsigned* __restrict__ h2b, int n) {
    __shared__ float hs[16][33];
    __shared__ float wl2[32][17];
    const int t = threadIdx.x;
    for (int i = t; i < HIDC * OUTC; i += 256) wl2[i >> 4][i & 15] = W2[i];
    const int nl = t >> 4;
    const int cp = t & 15;
    const long long node = (long long)blockIdx.x * 16 + nl;
    float vL = 0.f, vH = 0.f;
    if (node < n) {
        unsigned us = h1b[node * 16 + cp];
        float accL = bf16lo(us), accH = bf16hi(us);
        int st = ptr[node], deg = cnt[node];
        int j = 0;
        for (; j + 3 < deg; j += 4) {
            int s0 = csr_src[st + j], s1 = csr_src[st + j + 1];
            int s2 = csr_src[st + j + 2], s3 = csr_src[st + j + 3];
            unsigned u0 = h1b[(long long)s0 * 16 + cp];
            unsigned u1 = h1b[(long long)s1 * 16 + cp];
            unsigned u2 = h1b[(long long)s2 * 16 + cp];
            unsigned u3 = h1b[(long long)s3 * 16 + cp];
            accL += (bf16lo(u0) + bf16lo(u1)) + (bf16lo(u2) + bf16lo(u3));
            accH += (bf16hi(u0) + bf16hi(u1)) + (bf16hi(u2) + bf16hi(u3));
        }
        for (; j < deg; ++j) {
            unsigned u = h1b[(long long)csr_src[st + j] * 16 + cp];
            accL += bf16lo(u); accH += bf16hi(u);
        }
        float di = dinv[node];
        vL = accL * di + b1[2 * cp];
        vH = accH * di + b1[2 * cp + 1];
        vL = vL > 0.f ? vL : 0.f;
        vH = vH > 0.f ? vH : 0.f;
    }
    hs[nl][2 * cp]     = vL;
    hs[nl][2 * cp + 1] = vH;
    __syncthreads();
    if (t < 128) {
        int nl2 = t >> 3;
        int op  = t & 7;
        long long nd = (long long)blockIdx.x * 16 + nl2;
        if (nd < n) {
            float o0 = 0.f, o1 = 0.f;
#pragma unroll
            for (int k = 0; k < HIDC; ++k) {
                float h = hs[nl2][k];
                o0 = fmaf(h, wl2[k][2 * op],     o0);
                o1 = fmaf(h, wl2[k][2 * op + 1], o1);
            }
            float di = dinv[nd];
            h2b[nd * 8 + op] = bf16pair(o0 * di, o1 * di);
        }
    }
}

// ---------------- layer-2 pull aggregation (bf16 gathers) -> d_out ---------
__global__ __launch_bounds__(256) void k_agg2csr(const int* __restrict__ ptr,
                                                 const int* __restrict__ cnt,
                                                 const int* __restrict__ csr_src,
                                                 const float* __restrict__ dinv,
                                                 const unsigned* __restrict__ h2b,
                                                 const float* __restrict__ b2,
                                                 float* __restrict__ out, int n) {
    long long g = (long long)blockIdx.x * blockDim.x + threadIdx.x;
    int node = (int)(g >> 3);
    int cp = (int)(g & 7);
    if (node >= n) return;
    unsigned us = h2b[(long long)node * 8 + cp];
    float accL = bf16lo(us), accH = bf16hi(us);
    int st = ptr[node], deg = cnt[node];
    int j = 0;
    for (; j + 3 < deg; j += 4) {
        int s0 = csr_src[st + j], s1 = csr_src[st + j + 1];
        int s2 = csr_src[st + j + 2], s3 = csr_src[st + j + 3];
        unsigned u0 = h2b[(long long)s0 * 8 + cp];
        unsigned u1 = h2b[(long long)s1 * 8 + cp];
        unsigned u2 = h2b[(long long)s2 * 8 + cp];
        unsigned u3 = h2b[(long long)s3 * 8 + cp];
        accL += (bf16lo(u0) + bf16lo(u1)) + (bf16lo(u2) + bf16lo(u3));
        accH += (bf16hi(u0) + bf16hi(u1)) + (bf16hi(u2) + bf16hi(u3));
    }
    for (; j < deg; ++j) {
        unsigned u = h2b[(long long)csr_src[st + j] * 8 + cp];
        accL += bf16lo(u); accH += bf16hi(u);
    }
    float di = dinv[node];
    *(float2*)(out + (long long)node * OUTC + 2 * cp) =
        make_float2(accL * di + b2[2 * cp], accH * di + b2[2 * cp + 1]);
}

extern "C" void kernel_launch(void* const* d_in, const int* in_sizes, int n_in,
                              void* d_out, int out_size, void* d_ws, size_t ws_size,
                              hipStream_t stream) {
    const float* x  = (const float*)d_in[0];
    const int*   ei = (const int*)d_in[1];
    const float* W1 = (const float*)d_in[2];
    const float* b1 = (const float*)d_in[3];
    const float* W2 = (const float*)d_in[4];
    const float* b2 = (const float*)d_in[5];
    const int n = in_sizes[0] / IN_C;            // 100000
    const long long E = in_sizes[1] / 2;         // 3200000
    float* out = (float*)d_out;

    const int nbkt = (n + NPB - 1) / NPB;        // 391

    char* ws = (char*)d_ws;
    size_t off = 0;
    auto alloc = [&](size_t bytes) { void* p = ws + off; off += (bytes + 255) & ~(size_t)255; return p; };
    int*      flag     = (int*)alloc(256);
    int*      bkt_cur  = (int*)alloc((size_t)MAXBKT * 4);
    float*    dinv     = (float*)alloc((size_t)n * 4);
    int*      cnt      = (int*)alloc((size_t)n * 4);
    int*      ptr      = (int*)alloc((size_t)n * 4);
    unsigned* packed   = (unsigned*)alloc((size_t)nbkt * CAP * 4);      // 25.6 MB
    int*      csr_src  = (int*)alloc((size_t)nbkt * CAP * 4);           // 25.6 MB
    unsigned short* wf = (unsigned short*)alloc(8 * 2 * 2 * 64 * 8 * 2);  // 32 KB
    unsigned* h1b      = (unsigned*)alloc((size_t)n * (HIDC / 2) * 4);    // bf16 [n][32]
    unsigned* h2b      = (unsigned*)alloc((size_t)n * (OUTC / 2) * 4);    // bf16 [n][16]

    k_detect<<<1, 256, 0, stream>>>(ei, flag, bkt_cur, nbkt);
    k_wfrag<<<8, 256, 0, stream>>>(W1, wf);
    k_bin_scatter<<<(int)((E + EPB - 1) / EPB), 1024, 0, stream>>>(ei, E, flag, bkt_cur, packed, nbkt);
    k_bucket_csr<<<nbkt, NPB, 0, stream>>>(packed, bkt_cur, csr_src, ptr, cnt, dinv, n);

    k_gemm1<<<(n + 63) / 64, 256, 0, stream>>>(x, wf, dinv, (unsigned short*)h1b, n);
    k_agg1g2<<<(n + 15) / 16, 256, 0, stream>>>(ptr, cnt, csr_src, dinv, h1b, b1, W2, h2b, n);
    k_agg2csr<<<(int)(((long long)n * 8 + 255) / 256), 256, 0, stream>>>(
        ptr, cnt, csr_src, dinv, h2b, b2, out, n);
}

// Round 19
// 161.808 us; speedup vs baseline: 1.5995x; 1.0610x over previous
//
#include <hip/hip_runtime.h>

#define IN_C 256
#define HIDC 32
#define OUTC 16
#define NPB  256          // nodes per bucket (d_local = 8 bits)
#define MAXBKT 800
#define CAP  16384        // per-bucket packed capacity (mean 8184 -> 90 sigma safe)
#define EPB  12288        // edges per scatter block
#define EPT  12           // edges per thread (register cache)

typedef __attribute__((ext_vector_type(8))) short short8;
typedef __attribute__((ext_vector_type(4))) float f32x4;
union S8U4 { short8 s; unsigned u[4]; };

// ---------------- bf16 helpers ---------------------------------------------
__device__ __forceinline__ unsigned bf16pair(float a, float b) {   // RNE pack
    unsigned ua = __float_as_uint(a); ua += 0x7FFF + ((ua >> 16) & 1);
    unsigned ub = __float_as_uint(b); ub += 0x7FFF + ((ub >> 16) & 1);
    return (ua >> 16) | (ub & 0xFFFF0000u);
}
__device__ __forceinline__ float bf16lo(unsigned u) { return __uint_as_float(u << 16); }
__device__ __forceinline__ float bf16hi(unsigned u) { return __uint_as_float(u & 0xFFFF0000u); }
__device__ __forceinline__ unsigned rbf(float a) {                 // bf16 bits, RNE
    unsigned u = __float_as_uint(a);
    u += 0x7FFF + ((u >> 16) & 1);
    return u >> 16;
}
__device__ __forceinline__ void split8(const float* xf, short8& hi, short8& lo) {
    S8U4 H, L;
#pragma unroll
    for (int i = 0; i < 4; ++i) {
        float a = xf[2 * i], b = xf[2 * i + 1];
        unsigned ha = rbf(a), hb = rbf(b);
        float ra = a - __uint_as_float(ha << 16);
        float rb = b - __uint_as_float(hb << 16);
        H.u[i] = ha | (hb << 16);
        L.u[i] = rbf(ra) | (rbf(rb) << 16);
    }
    hi = H.s; lo = L.s;
}

// ---------------- edge index loader (handles int32 or int64 storage) -------
__device__ __forceinline__ int edge_at(const int* __restrict__ ei, long long idx, int is64) {
    return is64 ? ei[idx << 1] : ei[idx];
}

// ---------------- init: detect dtype + cursor init + W1 fragments ----------
__global__ void k_init(const int* __restrict__ ei, int* __restrict__ flag,
                       int* __restrict__ bkt_cur, int nbkt,
                       const float* __restrict__ W1, unsigned short* __restrict__ wf) {
    if (blockIdx.x == 0) {
        __shared__ int nz;
        if (threadIdx.x == 0) nz = 0;
        __syncthreads();
        if (ei[2 * threadIdx.x + 1] != 0) atomicOr(&nz, 1);
        for (int i = threadIdx.x; i < nbkt; i += 256) bkt_cur[i] = i * CAP;
        __syncthreads();
        if (threadIdx.x == 0) *flag = (nz == 0) ? 1 : 0;
    } else {
        int idx = (blockIdx.x - 1) * 256 + threadIdx.x;   // 0..2047
        int lane = idx & 63;
        int part = (idx >> 6) & 1;
        int tile = (idx >> 7) & 1;
        int s    = idx >> 8;
        int col = tile * 16 + (lane & 15);
        int k0  = s * 32 + (lane >> 4) * 8;
#pragma unroll
        for (int j = 0; j < 8; ++j) {
            float v = W1[(long long)(k0 + j) * HIDC + col];
            unsigned h = rbf(v);
            float r = v - __uint_as_float(h << 16);
            wf[(long long)idx * 8 + j] = (unsigned short)(part == 0 ? h : rbf(r));
        }
    }
}

// ---------------- super-kernel: edge scatter ∥ MFMA gemm1 ------------------
// Round-19: scatter (memory/atomic-bound) and gemm1 (MFMA-bound) are data-
// independent; same-stream dispatch serialized them. One kernel, blockIdx-
// split -> co-resident & overlapped. gemm1 writes UNSCALED bf16 h1 (dinv not
// known yet); k_bucket_csr applies the dinv rescale.
__global__ __launch_bounds__(1024) void k_super(const int* __restrict__ ei, long long E,
                                                const int* __restrict__ flag,
                                                int* __restrict__ bkt_cur,
                                                unsigned* __restrict__ packed, int nbkt, int nsb,
                                                const float* __restrict__ x,
                                                const unsigned short* __restrict__ wf,
                                                unsigned short* __restrict__ h1b_us, int n) {
    if ((int)blockIdx.x < nsb) {
        // ---- bucket scatter (register edge cache, round-18 structure) ----
        __shared__ int hist[MAXBKT];
        int is64 = *flag;
        for (int i = threadIdx.x; i < nbkt; i += 1024) hist[i] = 0;
        __syncthreads();
        long long lo = (long long)blockIdx.x * EPB;
        int m = (int)((E - lo) < EPB ? (E - lo) : EPB);
        unsigned ew[EPT];
        int      eb[EPT];
#pragma unroll
        for (int j = 0; j < EPT; ++j) {
            int i = j * 1024 + (int)threadIdx.x;
            eb[j] = -1;
            if (i < m) {
                int s = edge_at(ei, lo + i, is64);
                int d = edge_at(ei, E + lo + i, is64);
                ew[j] = (unsigned)s | ((unsigned)(d & (NPB - 1)) << 20);
                eb[j] = d >> 8;
                atomicAdd(&hist[eb[j]], 1);
            }
        }
        __syncthreads();
        for (int b = threadIdx.x; b < nbkt; b += 1024) {
            int c = hist[b];
            hist[b] = c ? atomicAdd(&bkt_cur[b], c) : 0;
        }
        __syncthreads();
#pragma unroll
        for (int j = 0; j < EPT; ++j) {
            if (eb[j] >= 0) {
                int slot = atomicAdd(&hist[eb[j]], 1);
                packed[slot] = ew[j];
            }
        }
    } else {
        // ---- gemm1 via MFMA (unscaled output) ----
        const int gb = (int)blockIdx.x - nsb;
        const int t = (int)threadIdx.x;
        const int l = t & 63;
        const int w = t >> 6;                                  // 0..15 waves
        const long long nb0 = (long long)gb * 256 + w * 16;
        const int kg = l >> 4;
        const long long nodeA = nb0 + (l & 15);
        const bool loadA = nodeA < n;
        f32x4 acc0 = {0.f, 0.f, 0.f, 0.f}, acc1 = {0.f, 0.f, 0.f, 0.f};
#pragma unroll
        for (int s = 0; s < 8; ++s) {
            float xf[8];
            if (loadA) {
                float4 v0 = *(const float4*)(x + nodeA * IN_C + s * 32 + kg * 8);
                float4 v1 = *(const float4*)(x + nodeA * IN_C + s * 32 + kg * 8 + 4);
                xf[0] = v0.x; xf[1] = v0.y; xf[2] = v0.z; xf[3] = v0.w;
                xf[4] = v1.x; xf[5] = v1.y; xf[6] = v1.z; xf[7] = v1.w;
            } else {
#pragma unroll
                for (int j = 0; j < 8; ++j) xf[j] = 0.f;
            }
            short8 ah, al;
            split8(xf, ah, al);
            const unsigned short* base = wf + ((long long)(s * 4) * 64 + l) * 8;
            short8 bh0 = *(const short8*)(base);
            short8 bl0 = *(const short8*)(base + 64 * 8);
            short8 bh1 = *(const short8*)(base + 2 * 64 * 8);
            short8 bl1 = *(const short8*)(base + 3 * 64 * 8);
            acc0 = __builtin_amdgcn_mfma_f32_16x16x32_bf16(ah, bh0, acc0, 0, 0, 0);
            acc0 = __builtin_amdgcn_mfma_f32_16x16x32_bf16(ah, bl0, acc0, 0, 0, 0);
            acc0 = __builtin_amdgcn_mfma_f32_16x16x32_bf16(al, bh0, acc0, 0, 0, 0);
            acc1 = __builtin_amdgcn_mfma_f32_16x16x32_bf16(ah, bh1, acc1, 0, 0, 0);
            acc1 = __builtin_amdgcn_mfma_f32_16x16x32_bf16(ah, bl1, acc1, 0, 0, 0);
            acc1 = __builtin_amdgcn_mfma_f32_16x16x32_bf16(al, bh1, acc1, 0, 0, 0);
        }
        // D layout (m89-verified): row = (l>>4)*4 + r, col = l&15
#pragma unroll
        for (int r = 0; r < 4; ++r) {
            long long nd = nb0 + (l >> 4) * 4 + r;
            if (nd < n) {
                h1b_us[nd * 32 + (l & 15)]      = (unsigned short)rbf(acc0[r]);
                h1b_us[nd * 32 + 16 + (l & 15)] = (unsigned short)rbf(acc1[r]);
            }
        }
    }
}

// ---------------- per-bucket counting sort -> CSR + dinv + h1b rescale -----
__global__ __launch_bounds__(256) void k_bucket_csr(const unsigned* __restrict__ packed,
                                                    const int* __restrict__ bkt_cur,
                                                    int* __restrict__ csr_src,
                                                    int* __restrict__ ptr,
                                                    int* __restrict__ cnt,
                                                    float* __restrict__ dinv,
                                                    unsigned* __restrict__ h1b, int n) {
    __shared__ int hist[NPB];
    __shared__ int off[NPB];
    hist[threadIdx.x] = 0;
    __syncthreads();
    int base = blockIdx.x * CAP;
    int m = bkt_cur[blockIdx.x] - base;
    for (int i = threadIdx.x; i < m; i += 256)
        atomicAdd(&hist[packed[base + i] >> 20], 1);
    __syncthreads();
    off[threadIdx.x] = hist[threadIdx.x];
    __syncthreads();
    for (int o = 1; o < NPB; o <<= 1) {
        int v = (threadIdx.x >= o) ? off[threadIdx.x - o] : 0;
        __syncthreads();
        off[threadIdx.x] += v;
        __syncthreads();
    }
    long long node = (long long)blockIdx.x * NPB + threadIdx.x;
    {
        int exc = off[threadIdx.x] - hist[threadIdx.x];
        if (node < n) {
            float di = rsqrtf((float)hist[threadIdx.x] + 1.0f);
            ptr[node]  = base + exc;
            cnt[node]  = hist[threadIdx.x];
            dinv[node] = di;
            // rescale unscaled gemm1 output: h1b[node] *= di (bf16 in, bf16 out)
            unsigned* row = h1b + node * 16;
#pragma unroll
            for (int q = 0; q < 16; ++q) {
                unsigned u = row[q];
                row[q] = bf16pair(bf16lo(u) * di, bf16hi(u) * di);
            }
        }
        hist[threadIdx.x] = exc;
    }
    __syncthreads();
    for (int i = threadIdx.x; i < m; i += 256) {
        unsigned w = packed[base + i];
        int r = atomicAdd(&hist[w >> 20], 1);
        csr_src[base + r] = (int)(w & 0xFFFFF);
    }
}

// ---------------- fused layer-1 aggregation + gemm2 ------------------------
__global__ __launch_bounds__(256) void k_agg1g2(const int* __restrict__ ptr,
                                                const int* __restrict__ cnt,
                                                const int* __restrict__ csr_src,
                                                const float* __restrict__ dinv,
                                                const unsigned* __restrict__ h1b,
                                                const float* __restrict__ b1,
                                                const float* __restrict__ W2,
                                                unsigned* __restrict__ h2b, int n) {
    __shared__ float hs[16][33];
    __shared__ float wl2[32][17];
    const int t = threadIdx.x;
    for (int i = t; i < HIDC * OUTC; i += 256) wl2[i >> 4][i & 15] = W2[i];
    const int nl = t >> 4;
    const int cp = t & 15;
    const long long node = (long long)blockIdx.x * 16 + nl;
    float vL = 0.f, vH = 0.f;
    if (node < n) {
        unsigned us = h1b[node * 16 + cp];
        float accL = bf16lo(us), accH = bf16hi(us);
        int st = ptr[node], deg = cnt[node];
        int j = 0;
        for (; j + 3 < deg; j += 4) {
            int s0 = csr_src[st + j], s1 = csr_src[st + j + 1];
            int s2 = csr_src[st + j + 2], s3 = csr_src[st + j + 3];
            unsigned u0 = h1b[(long long)s0 * 16 + cp];
            unsigned u1 = h1b[(long long)s1 * 16 + cp];
            unsigned u2 = h1b[(long long)s2 * 16 + cp];
            unsigned u3 = h1b[(long long)s3 * 16 + cp];
            accL += (bf16lo(u0) + bf16lo(u1)) + (bf16lo(u2) + bf16lo(u3));
            accH += (bf16hi(u0) + bf16hi(u1)) + (bf16hi(u2) + bf16hi(u3));
        }
        for (; j < deg; ++j) {
            unsigned u = h1b[(long long)csr_src[st + j] * 16 + cp];
            accL += bf16lo(u); accH += bf16hi(u);
        }
        float di = dinv[node];
        vL = accL * di + b1[2 * cp];
        vH = accH * di + b1[2 * cp + 1];
        vL = vL > 0.f ? vL : 0.f;
        vH = vH > 0.f ? vH : 0.f;
    }
    hs[nl][2 * cp]     = vL;
    hs[nl][2 * cp + 1] = vH;
    __syncthreads();
    if (t < 128) {
        int nl2 = t >> 3;
        int op  = t & 7;
        long long nd = (long long)blockIdx.x * 16 + nl2;
        if (nd < n) {
            float o0 = 0.f, o1 = 0.f;
#pragma unroll
            for (int k = 0; k < HIDC; ++k) {
                float h = hs[nl2][k];
                o0 = fmaf(h, wl2[k][2 * op],     o0);
                o1 = fmaf(h, wl2[k][2 * op + 1], o1);
            }
            float di = dinv[nd];
            h2b[nd * 8 + op] = bf16pair(o0 * di, o1 * di);
        }
    }
}

// ---------------- layer-2 pull aggregation (bf16 gathers) -> d_out ---------
__global__ __launch_bounds__(256) void k_agg2csr(const int* __restrict__ ptr,
                                                 const int* __restrict__ cnt,
                                                 const int* __restrict__ csr_src,
                                                 const float* __restrict__ dinv,
                                                 const unsigned* __restrict__ h2b,
                                                 const float* __restrict__ b2,
                                                 float* __restrict__ out, int n) {
    long long g = (long long)blockIdx.x * blockDim.x + threadIdx.x;
    int node = (int)(g >> 3);
    int cp = (int)(g & 7);
    if (node >= n) return;
    unsigned us = h2b[(long long)node * 8 + cp];
    float accL = bf16lo(us), accH = bf16hi(us);
    int st = ptr[node], deg = cnt[node];
    int j = 0;
    for (; j + 3 < deg; j += 4) {
        int s0 = csr_src[st + j], s1 = csr_src[st + j + 1];
        int s2 = csr_src[st + j + 2], s3 = csr_src[st + j + 3];
        unsigned u0 = h2b[(long long)s0 * 8 + cp];
        unsigned u1 = h2b[(long long)s1 * 8 + cp];
        unsigned u2 = h2b[(long long)s2 * 8 + cp];
        unsigned u3 = h2b[(long long)s3 * 8 + cp];
        accL += (bf16lo(u0) + bf16lo(u1)) + (bf16lo(u2) + bf16lo(u3));
        accH += (bf16hi(u0) + bf16hi(u1)) + (bf16hi(u2) + bf16hi(u3));
    }
    for (; j < deg; ++j) {
        unsigned u = h2b[(long long)csr_src[st + j] * 8 + cp];
        accL += bf16lo(u); accH += bf16hi(u);
    }
    float di = dinv[node];
    *(float2*)(out + (long long)node * OUTC + 2 * cp) =
        make_float2(accL * di + b2[2 * cp], accH * di + b2[2 * cp + 1]);
}

extern "C" void kernel_launch(void* const* d_in, const int* in_sizes, int n_in,
                              void* d_out, int out_size, void* d_ws, size_t ws_size,
                              hipStream_t stream) {
    const float* x  = (const float*)d_in[0];
    const int*   ei = (const int*)d_in[1];
    const float* W1 = (const float*)d_in[2];
    const float* b1 = (const float*)d_in[3];
    const float* W2 = (const float*)d_in[4];
    const float* b2 = (const float*)d_in[5];
    const int n = in_sizes[0] / IN_C;            // 100000
    const long long E = in_sizes[1] / 2;         // 3200000
    float* out = (float*)d_out;

    const int nbkt = (n + NPB - 1) / NPB;        // 391
    const int nsb  = (int)((E + EPB - 1) / EPB); // 261 scatter blocks
    const int ngb  = (n + 255) / 256;            // 391 gemm1 blocks

    char* ws = (char*)d_ws;
    size_t off = 0;
    auto alloc = [&](size_t bytes) { void* p = ws + off; off += (bytes + 255) & ~(size_t)255; return p; };
    int*      flag     = (int*)alloc(256);
    int*      bkt_cur  = (int*)alloc((size_t)MAXBKT * 4);
    float*    dinv     = (float*)alloc((size_t)n * 4);
    int*      cnt      = (int*)alloc((size_t)n * 4);
    int*      ptr      = (int*)alloc((size_t)n * 4);
    unsigned* packed   = (unsigned*)alloc((size_t)nbkt * CAP * 4);        // 25.6 MB
    int*      csr_src  = (int*)alloc((size_t)nbkt * CAP * 4);             // 25.6 MB
    unsigned short* wf = (unsigned short*)alloc(8 * 2 * 2 * 64 * 8 * 2);  // 32 KB
    unsigned* h1b      = (unsigned*)alloc((size_t)n * (HIDC / 2) * 4);    // bf16 [n][32]
    unsigned* h2b      = (unsigned*)alloc((size_t)n * (OUTC / 2) * 4);    // bf16 [n][16]

    k_init<<<9, 256, 0, stream>>>(ei, flag, bkt_cur, nbkt, W1, wf);
    k_super<<<nsb + ngb, 1024, 0, stream>>>(ei, E, flag, bkt_cur, packed, nbkt, nsb,
                                            x, wf, (unsigned short*)h1b, n);
    k_bucket_csr<<<nbkt, NPB, 0, stream>>>(packed, bkt_cur, csr_src, ptr, cnt, dinv, h1b, n);
    k_agg1g2<<<(n + 15) / 16, 256, 0, stream>>>(ptr, cnt, csr_src, dinv, h1b, b1, W2, h2b, n);
    k_agg2csr<<<(int)(((long long)n * 8 + 255) / 256), 256, 0, stream>>>(
        ptr, cnt, csr_src, dinv, h2b, b2, out, n);
}